// Round 9
// baseline (603.503 us; speedup 1.0000x reference)
//
#include <hip/hip_runtime.h>
#include <math.h>

#define TFRAMES 4096
#define DM 128
#define LQ 64
#define NG 16
#define NH 8
#define DQH 16
#define FD 2048
#define GFD 512
#define PAD 63
#define KVROWS (TFRAMES + PAD)      /* 4159 */
#define ASTRIDE (KVROWS * DM)       /* 532352 SHORTS per bf16 K/V array */
#define FPB 4                       /* frames per block */
#define MROWS (FPB * NG)            /* 64 state rows per block */
#define STS 136                     /* state row stride (shorts, mult of 8) */
#define VTS 72                      /* V^T row stride (shorts) */
#define PBS 72                      /* P buffer row stride (shorts) */
#define UROWS (LQ + FPB - 1)        /* 67 K/V union rows */

/* ws layout (floats). */
#define OFF_WVH  0                                 /* Wvis^T hi: 128x2048 sh = 131072 fl */
#define OFF_WVL  131072
#define OFF_WKVH 262144                            /* Wk/Wv^T hi: 4x16384 sh = 32768 fl */
#define OFF_WKVL 294912
#define OFF_KV   (TFRAMES * DM)                    /* 524288 */
#define OFF_TEXT (OFF_KV + 2 * ASTRIDE)
#define OFF_KF   (OFF_TEXT + NG * DM)
#define OFF_VF   (OFF_KF + NG * DM)
#define OFF_W1T  (OFF_VF + NG * DM)
#define OFF_W2T  (OFF_W1T + 262144)
#define OFF_WQT  (OFF_W2T + 262144)
#define OFF_WQFT (OFF_WQT + 16384)

typedef __attribute__((ext_vector_type(8))) short bf16x8;
typedef __attribute__((ext_vector_type(4))) float f32x4;
#define MFMA16(a, b, c) __builtin_amdgcn_mfma_f32_16x16x32_bf16(a, b, c, 0, 0, 0)

// f32->bf16 RNE via the compiler's native __bf16 cast (r8-verified: PASS,
// VALUBusy 38->33%, dur 442->432; bit-identical absmax).
__device__ __forceinline__ short bfc(float x) {
    union { __bf16 b; short s; } v;
    v.b = (__bf16)x;
    return v.s;
}
__device__ __forceinline__ float b2f(short s) {
    union { unsigned u; float f; } v;
    v.u = ((unsigned)(unsigned short)s) << 16;
    return v.f;
}
// Extract 8 shorts starting at short-offset f (0..3) from the 12-short window
// {a.x..a.w, b.x, b.y}. v_alignbit_b32 shift is 5-bit (wraps at 32!), so split
// f into a word offset (wo = f>>1, uniform select) + residual 0/16-bit shift.
__device__ __forceinline__ bf16x8 shiftf(int4 a, int4 b, int f) {
    const int wo = f >> 1;
    const int sh = (f & 1) * 16;
    int w0 = wo ? a.y : a.x;
    int w1 = wo ? a.z : a.y;
    int w2 = wo ? a.w : a.z;
    int w3 = wo ? b.x : a.w;
    int w4 = wo ? b.y : b.x;
    int o0 = __builtin_amdgcn_alignbit(w1, w0, sh);
    int o1 = __builtin_amdgcn_alignbit(w2, w1, sh);
    int o2 = __builtin_amdgcn_alignbit(w3, w2, sh);
    int o3 = __builtin_amdgcn_alignbit(w4, w3, sh);
    int4 o = {o0, o1, o2, o3};
    return *(bf16x8*)&o;
}

// -------- kernel W: unified coalesced LDS tile-transpose of all weights ------
__global__ __launch_bounds__(256) void k_wcvt(const float* __restrict__ Wq_enc,
                                              const float* __restrict__ W1f,
                                              const float* __restrict__ W2f,
                                              const float* __restrict__ Wqf,
                                              const float* __restrict__ Wk_enc,
                                              const float* __restrict__ Wv_enc,
                                              const float* __restrict__ Wvis,
                                              short* __restrict__ W1T,
                                              short* __restrict__ W2T,
                                              short* __restrict__ WQT,
                                              short* __restrict__ WQFT,
                                              short* __restrict__ WKVH,
                                              short* __restrict__ WKVL,
                                              short* __restrict__ WVH,
                                              short* __restrict__ WVL) {
    __shared__ float tile[64][65];
    const int tid = threadIdx.x;
    const int gy = blockIdx.y, gx = blockIdx.x;
    const float* src; short* dst; short* dstL = nullptr;
    int sstride, dstride, tr, tc;
    if (gy < 2) {            // W1: [128][2048] -> W1T [2048][128]
        src = W1f + (size_t)gy * 262144; dst = W1T + gy * 262144;
        sstride = 2048; dstride = 128; tr = gx >> 5; tc = gx & 31;
    } else if (gy < 4) {     // W2: [2048][128] -> W2T [128][2048]
        int l = gy - 2;
        src = W2f + (size_t)l * 262144; dst = W2T + l * 262144;
        sstride = 128; dstride = 2048; tr = gx >> 1; tc = gx & 1;
    } else if (gy == 4) {    // WQ l0,l1, WQF: [128][128]
        if (gx >= 12) return;
        int t = gx >> 2;
        src = (t < 2) ? Wq_enc + (size_t)t * 16384 : Wqf;
        dst = (t < 2) ? WQT + t * 16384 : WQFT;
        sstride = 128; dstride = 128; tr = (gx >> 1) & 1; tc = gx & 1;
    } else if (gy == 5) {    // WKV hi/lo: a = 2l + isV
        if (gx >= 16) return;
        int a = gx >> 2;
        src = ((a & 1) ? Wv_enc : Wk_enc) + (size_t)(a >> 1) * 16384;
        dst = WKVH + a * 16384; dstL = WKVL + a * 16384;
        sstride = 128; dstride = 128; tr = (gx >> 1) & 1; tc = gx & 1;
    } else {                 // Wvis: [2048][128] -> WVH/WVL [128][2048]
        src = Wvis; dst = WVH; dstL = WVL;
        sstride = 128; dstride = 2048; tr = gx >> 1; tc = gx & 1;
    }
    const int rb = tr * 64, cb = tc * 64;
    for (int o = tid; o < 64 * 64; o += 256) {
        int r = o >> 6, c = o & 63;
        tile[r][c] = src[(size_t)(rb + r) * sstride + cb + c];
    }
    __syncthreads();
    for (int o = tid; o < 64 * 64; o += 256) {
        int rn = o >> 6, ck = o & 63;
        float v = tile[ck][rn];
        short hi = bfc(v);
        size_t di = (size_t)(cb + rn) * dstride + rb + ck;
        dst[di] = hi;
        if (dstL) dstL[di] = bfc(v - b2f(hi));
    }
}

// -------- kernel P: visual=lf@Wvis, LN, K/V=visn@Wk/Wv — all MFMA, hi/lo -----
// 3-pass hi/lo (AhBh + AlBh + AhBl) keeps ~fp32 accuracy end to end.
__global__ __launch_bounds__(256) void k_viskv(const float* __restrict__ lf,
                                               const short* __restrict__ WVH,
                                               const short* __restrict__ WVL,
                                               const short* __restrict__ WKVH,
                                               const short* __restrict__ WKVL,
                                               short* __restrict__ kvB) {
    __shared__ __align__(16) char smem[17408 + 4352];   // Ah|Al  /  vis | Vh | Vl
    __shared__ float sPa[256], sPb[256], sMean[16], sRstd[16];
    short* Ah = (short*)smem;                 // [16][136] bf16 (4352 B)
    short* Al = (short*)(smem + 4352);        // [16][136]
    float* vis = (float*)smem;                // [16][132] fp32 (8448 B, overlays Ah/Al)
    short* Vh = (short*)(smem + 8704);        // [16][136]
    short* Vl = (short*)(smem + 13056);       // [16][136]

    const int tid = threadIdx.x;              // 256 = 4 waves
    const int w = tid >> 6;
    const int lane = tid & 63;
    const int lq = lane & 15;
    const int quad = lane >> 4;
    const int r0 = blockIdx.x * 16;           // 256 blocks x 16 rows

    // ---- phase 1: visual = lf @ Wvis  (K=2048 in 16 chunks of 128) ----
    f32x4 acc[2];     // wave w owns out cols w*32 .. w*32+31 (2 n-tiles)
    acc[0] = (f32x4){0.f, 0.f, 0.f, 0.f};
    acc[1] = (f32x4){0.f, 0.f, 0.f, 0.f};
    for (int c = 0; c < 16; ++c) {
        __syncthreads();                      // prior MFMA reads done before overwrite
        for (int o = tid; o < 16 * 128; o += 256) {
            int r = o >> 7, j = o & 127;
            float v = lf[(size_t)(r0 + r) * FD + c * 128 + j];
            short hi = bfc(v);
            Ah[r * 136 + j] = hi;
            Al[r * 136 + j] = bfc(v - b2f(hi));
        }
        __syncthreads();
#pragma unroll
        for (int ks = 0; ks < 4; ++ks) {
            bf16x8 ah = *(const bf16x8*)&Ah[lq * 136 + ks * 32 + quad * 8];
            bf16x8 al = *(const bf16x8*)&Al[lq * 136 + ks * 32 + quad * 8];
#pragma unroll
            for (int nt = 0; nt < 2; ++nt) {
                const size_t bo = (size_t)(w * 32 + nt * 16 + lq) * FD + c * 128 + ks * 32 + quad * 8;
                bf16x8 bh = *(const bf16x8*)&WVH[bo];
                bf16x8 bl = *(const bf16x8*)&WVL[bo];
                acc[nt] = MFMA16(ah, bh, acc[nt]);
                acc[nt] = MFMA16(al, bh, acc[nt]);
                acc[nt] = MFMA16(ah, bl, acc[nt]);
            }
        }
    }
    __syncthreads();
    // C-layout -> vis[row][col] fp32 (row = quad*4+r, col = w*32+nt*16+lq)
#pragma unroll
    for (int nt = 0; nt < 2; ++nt)
#pragma unroll
        for (int r = 0; r < 4; ++r)
            vis[(quad * 4 + r) * 132 + w * 32 + nt * 16 + lq] = acc[nt][r];
    __syncthreads();

    // ---- phase 2: LN over 128 cols per row; visn -> hi/lo bf16 ----
    {
        int row = tid >> 4, p = tid & 15;     // 8 cols per thread
        float s = 0.f, s2 = 0.f;
#pragma unroll
        for (int k = 0; k < 8; ++k) { float v = vis[row * 132 + p * 8 + k]; s += v; s2 += v * v; }
        sPa[tid] = s; sPb[tid] = s2;
    }
    __syncthreads();
    if (tid < 16) {
        float s = 0.f, s2 = 0.f;
#pragma unroll
        for (int p = 0; p < 16; ++p) { s += sPa[tid * 16 + p]; s2 += sPb[tid * 16 + p]; }
        float m = s * (1.f / 128.f);
        float v = s2 * (1.f / 128.f) - m * m;
        sMean[tid] = m; sRstd[tid] = rsqrtf(v + 1e-5f);
    }
    __syncthreads();
    for (int o = tid; o < 16 * 128; o += 256) {
        int r = o >> 7, j = o & 127;
        float v = (vis[r * 132 + j] - sMean[r]) * sRstd[r];
        short hi = bfc(v);
        Vh[r * 136 + j] = hi;
        Vl[r * 136 + j] = bfc(v - b2f(hi));
    }
    __syncthreads();

    // ---- phase 3: K/V = visn @ Wk/Wv per array (K=128), bf16 out ----
    for (int a = 0; a < 4; ++a) {
        f32x4 ka[2];
        ka[0] = (f32x4){0.f, 0.f, 0.f, 0.f};
        ka[1] = (f32x4){0.f, 0.f, 0.f, 0.f};
#pragma unroll
        for (int ks = 0; ks < 4; ++ks) {
            bf16x8 ah = *(const bf16x8*)&Vh[lq * 136 + ks * 32 + quad * 8];
            bf16x8 al = *(const bf16x8*)&Vl[lq * 136 + ks * 32 + quad * 8];
#pragma unroll
            for (int nt = 0; nt < 2; ++nt) {
                const size_t bo = (size_t)a * 16384 + (size_t)(w * 32 + nt * 16 + lq) * 128 + ks * 32 + quad * 8;
                bf16x8 bh = *(const bf16x8*)&WKVH[bo];
                bf16x8 bl = *(const bf16x8*)&WKVL[bo];
                ka[nt] = MFMA16(ah, bh, ka[nt]);
                ka[nt] = MFMA16(al, bh, ka[nt]);
                ka[nt] = MFMA16(ah, bl, ka[nt]);
            }
        }
#pragma unroll
        for (int nt = 0; nt < 2; ++nt)
#pragma unroll
            for (int r = 0; r < 4; ++r)
                kvB[(size_t)a * ASTRIDE + (size_t)(PAD + r0 + quad * 4 + r) * DM + w * 32 + nt * 16 + lq]
                    = bfc(ka[nt][r]);
    }
}

// -------- kernel 3: text = g @ W_txt ; Kf = text @ Wk_f ; Vf = text @ Wv_f ---
__global__ __launch_bounds__(128) void k_text(const float* __restrict__ g,
                                              const float* __restrict__ Wtxt,
                                              const float* __restrict__ Wkf,
                                              const float* __restrict__ Wvf,
                                              float* __restrict__ text,
                                              float* __restrict__ kf,
                                              float* __restrict__ vf) {
    __shared__ float gs[GFD];
    __shared__ float tr[DM];
    const int r = blockIdx.x;
    const int tid = threadIdx.x;
    for (int i = tid; i < GFD; i += 128) gs[i] = g[(size_t)r * GFD + i];
    __syncthreads();
    float acc = 0.f;
    for (int k = 0; k < GFD; ++k) acc += gs[k] * Wtxt[(size_t)k * DM + tid];
    tr[tid] = acc;
    text[(size_t)r * DM + tid] = acc;
    __syncthreads();
    float a1 = 0.f, a2 = 0.f;
    for (int k = 0; k < DM; ++k) {
        float x = tr[k];
        a1 += x * Wkf[(size_t)k * DM + tid];
        a2 += x * Wvf[(size_t)k * DM + tid];
    }
    kf[(size_t)r * DM + tid] = a1;
    vf[(size_t)r * DM + tid] = a2;
}

// ---------------- LN helpers for [64][STS] bf16 LDS tile ---------------------
__device__ __forceinline__ void ln_stats64(const short* buf, int tid, int dbl,
                                           float* pa, float* pb, float* ms, float* rs) {
    {
        int row = tid >> 3, p = tid & 7;
        const bf16x8* bp = (const bf16x8*)(buf + row * STS + p * 16);
        float s = 0.f, s2 = 0.f;
#pragma unroll
        for (int q8 = 0; q8 < 2; ++q8) {
            bf16x8 x = bp[q8];
#pragma unroll
            for (int e = 0; e < 8; ++e) { float v = b2f(x[e]); s += v; s2 += v * v; }
        }
        pa[tid] = s; pb[tid] = s2;
    }
    __syncthreads();
    if (tid < 64) {
        float ss = 0.f, ss2 = 0.f;
#pragma unroll
        for (int p2 = 0; p2 < 8; ++p2) { ss += pa[tid * 8 + p2]; ss2 += pb[tid * 8 + p2]; }
        float m = ss * (1.f / 128.f);
        float v = ss2 * (1.f / 128.f) - m * m;
        float r = rsqrtf(v + 1e-5f);
        if (dbl) r *= rsqrtf(v / (v + 1e-5f) + 1e-5f);   // exact LN(LN(x)) fold
        ms[tid] = m; rs[tid] = r;
    }
    __syncthreads();
}
__device__ __forceinline__ void ln_apply64(short* buf, int tid,
                                           const float* ms, const float* rs) {
    int row = tid >> 3, p = tid & 7;
    float m = ms[row], r = rs[row];
    bf16x8* bp = (bf16x8*)(buf + row * STS + p * 16);
#pragma unroll
    for (int q8 = 0; q8 < 2; ++q8) {
        bf16x8 x = bp[q8]; bf16x8 o;
#pragma unroll
        for (int e = 0; e < 8; ++e) o[e] = bfc((b2f(x[e]) - m) * r);
        bp[q8] = o;
    }
    __syncthreads();
}

// ---------------- kernel 4: 4 frames/block, MFMA attention + FFN -------------
__global__ __launch_bounds__(512, 4) void k_frames(
    const short* __restrict__ kvB,    const float* __restrict__ text,
    const float* __restrict__ kf,     const float* __restrict__ vf,
    const short* __restrict__ W1T,    const short* __restrict__ W2T,
    const short* __restrict__ WQT,    const short* __restrict__ WQFT,
    float* __restrict__ out) {
    __shared__ __align__(16) short sT[MROWS * STS];     // state (t / z / x / z2)
    __shared__ __align__(16) short sX[MROWS * STS];     // Q / H-chunk / Qf / z3
    __shared__ __align__(16) short sVT[128 * VTS];      // V^T union (dims x keys)
    __shared__ __align__(16) short sPB[8 * 16 * PBS];   // per-wave P; FFN H dbuf; kf/vf/scores
    __shared__ float sPa[512], sPb[512];
    __shared__ float sMean[64], sRstd[64];

    const int tid = threadIdx.x;        // 512 = 8 waves
    const int w = tid >> 6;             // wave 0..7
    const int lane = tid & 63;
    const int lq = lane & 15;
    const int quad = lane >> 4;
    // XCD-aware swizzle (T1): keeps each XCD on a contiguous frame chunk
    // (FETCH 115->99 MB verified r0->r6; time-neutral but strictly less HBM).
    const int bswz = (blockIdx.x & 7) * 128 + (blockIdx.x >> 3);
    const int T0 = bswz * FPB;

    // init: t rows m = f*16+q <- text[q][:]
    for (int o = tid; o < MROWS * 128; o += 512)
        sT[(o >> 7) * STS + (o & 127)] = bfc(text[((o >> 7) & 15) * 128 + (o & 127)]);
    __syncthreads();

    for (int l = 0; l < 2; ++l) {
        const short* kvK = kvB + (size_t)(2 * l) * ASTRIDE;
        const short* kvV = kvB + (size_t)(2 * l + 1) * ASTRIDE;

        // ---- stage V^T union (coalesced; barrier inside ln_stats covers it) --
        for (int o = tid; o < UROWS * 128; o += 512) {
            int u = o >> 7, d = o & 127;
            sVT[d * VTS + u] = kvV[(size_t)(T0 + u) * 128 + d];
        }
        ln_stats64(sT, tid, 0, sPa, sPb, sMean, sRstd);

        // ---- Q = LN(t) @ Wq[l] -> sX (LN applied inline on A-fragments) ----
        {
            const short* wq = WQT + (size_t)l * 16384;
            bf16x8 B[4];
#pragma unroll
            for (int ks = 0; ks < 4; ++ks)
                B[ks] = *(const bf16x8*)&wq[(w * 16 + lq) * 128 + ks * 32 + quad * 8];
#pragma unroll
            for (int mt = 0; mt < 4; ++mt) {
                int row = mt * 16 + lq;
                float m = sMean[row], r = sRstd[row];
                f32x4 acc = {0.f, 0.f, 0.f, 0.f};
#pragma unroll
                for (int ks = 0; ks < 4; ++ks) {
                    bf16x8 t8 = *(const bf16x8*)&sT[row * STS + ks * 32 + quad * 8];
                    bf16x8 a8;
#pragma unroll
                    for (int e = 0; e < 8; ++e) a8[e] = bfc((b2f(t8[e]) - m) * r);
                    acc = MFMA16(a8, B[ks], acc);
                }
#pragma unroll
                for (int r4 = 0; r4 < 4; ++r4)
                    sX[(mt * 16 + quad * 4 + r4) * STS + w * 16 + lq] = bfc(acc[r4]);
            }
        }
        __syncthreads();

        // ---- attention: wave pair (2f, 2f+1) handles frame f, 4 heads each --
        {
            const int f = w >> 1;
            const int hg = (w & 1) * 4;
            short* Pb = sPB + w * 16 * PBS;
            bf16x8 zv = {};
            for (int hh = 0; hh < 4; ++hh) {
                const int h = hg + hh;
                bf16x8 aq;
                {
                    bf16x8 t8 = *(const bf16x8*)&sX[(f * 16 + lq) * STS + h * 16 + (quad & 1) * 8];
                    aq = (quad < 2) ? t8 : zv;
                }
                f32x4 sc4[4];
#pragma unroll
                for (int kt = 0; kt < 4; ++kt) {
                    bf16x8 bk = *(const bf16x8*)&kvK[(size_t)(T0 + f + kt * 16 + lq) * 128 + h * 16 + (quad & 1) * 8];
                    bk = (quad < 2) ? bk : zv;
                    f32x4 z4 = {0.f, 0.f, 0.f, 0.f};
                    sc4[kt] = MFMA16(aq, bk, z4);
                }
                // softmax in C-layout registers; keep fp32 P values
                float pr[4][4];   // [r][kt]
#pragma unroll
                for (int r = 0; r < 4; ++r) {
                    float a0 = sc4[0][r] * 0.25f, a1 = sc4[1][r] * 0.25f;
                    float a2 = sc4[2][r] * 0.25f, a3 = sc4[3][r] * 0.25f;
                    float mx = fmaxf(fmaxf(a0, a1), fmaxf(a2, a3));
                    mx = fmaxf(mx, __shfl_xor(mx, 1));
                    mx = fmaxf(mx, __shfl_xor(mx, 2));
                    mx = fmaxf(mx, __shfl_xor(mx, 4));
                    mx = fmaxf(mx, __shfl_xor(mx, 8));
                    float e0 = expf(a0 - mx), e1 = expf(a1 - mx);
                    float e2 = expf(a2 - mx), e3 = expf(a3 - mx);
                    float s = e0 + e1 + e2 + e3;
                    s += __shfl_xor(s, 1);
                    s += __shfl_xor(s, 2);
                    s += __shfl_xor(s, 4);
                    s += __shfl_xor(s, 8);
                    float inv = 1.f / s;
                    pr[r][0] = e0 * inv; pr[r][1] = e1 * inv;
                    pr[r][2] = e2 * inv; pr[r][3] = e3 * inv;
                }
                // V^T window fragments once (register-resident across hi/lo passes)
                const short* vr = &sVT[(h * 16 + lq) * VTS];
                int4 v0 = *(const int4*)&vr[quad * 8];
                int4 v1 = *(const int4*)&vr[quad * 8 + 8];
                int4 u0 = *(const int4*)&vr[32 + quad * 8];
                int4 u1 = *(const int4*)&vr[32 + quad * 8 + 8];
                bf16x8 b0 = shiftf(v0, v1, f);
                bf16x8 b1 = shiftf(u0, u1, f);
                // PV with hi+lo bf16 split of P (extra precision margin).
                f32x4 ctx = {0.f, 0.f, 0.f, 0.f};
#pragma unroll
                for (int pass = 0; pass < 2; ++pass) {
#pragma unroll
                    for (int r = 0; r < 4; ++r)
#pragma unroll
                        for (int kt = 0; kt < 4; ++kt) {
                            float p = pr[r][kt];
                            short hi = bfc(p);
                            short v16 = pass == 0 ? hi : bfc(p - b2f(hi));
                            Pb[(quad * 4 + r) * PBS + kt * 16 + lq] = v16;
                        }
                    bf16x8 p0 = *(const bf16x8*)&Pb[lq * PBS + quad * 8];
                    bf16x8 p1 = *(const bf16x8*)&Pb[lq * PBS + 32 + quad * 8];
                    ctx = MFMA16(p0, b0, ctx);
                    ctx = MFMA16(p1, b1, ctx);
                }
                // z = ctx + tq  (tq recomputed from t + stats, fp32)
#pragma unroll
                for (int r = 0; r < 4; ++r) {
                    int row = f * 16 + quad * 4 + r;
                    int col = h * 16 + lq;
                    float tq = (b2f(sT[row * STS + col]) - sMean[row]) * sRstd[row];
                    sT[row * STS + col] = bfc(ctx[r] + tq);
                }
            }
        }
        __syncthreads();

        // ---- x = LN(LN(z)) in place ----
        ln_stats64(sT, tid, 1, sPa, sPb, sMean, sRstd);
        ln_apply64(sT, tid, sMean, sRstd);

        // ---- FFN: z2 = relu(x@W1)@W2 + x -> sT ----
        // H-chunk double-buffered through sX / sPB (sPB is dead during FFN:
        // attention P is consumed, kf/vf staging is post-loop). One barrier
        // per chunk instead of two; GEMM1(c+1) and GEMM2(c) share each
        // inter-barrier region so B1/B2 L2 latency hides under MFMAs.
        {
            const short* w1p = W1T + (size_t)l * 262144;
            const short* w2p = W2T + (size_t)l * 262144;
            bf16x8 XA[4][4];
#pragma unroll
            for (int mt = 0; mt < 4; ++mt)
#pragma unroll
                for (int ks = 0; ks < 4; ++ks)
                    XA[mt][ks] = *(const bf16x8*)&sT[(mt * 16 + lq) * STS + ks * 32 + quad * 8];
            f32x4 yacc[4];
#pragma unroll
            for (int mt = 0; mt < 4; ++mt) yacc[mt] = (f32x4){0.f, 0.f, 0.f, 0.f};
            // prologue: GEMM1 chunk 0 -> sX (buffer 0)
            {
                f32x4 hacc[4];
#pragma unroll
                for (int mt = 0; mt < 4; ++mt) hacc[mt] = (f32x4){0.f, 0.f, 0.f, 0.f};
#pragma unroll
                for (int ks = 0; ks < 4; ++ks) {
                    bf16x8 B1 = *(const bf16x8*)&w1p[(size_t)(w * 16 + lq) * 128 + ks * 32 + quad * 8];
#pragma unroll
                    for (int mt = 0; mt < 4; ++mt) hacc[mt] = MFMA16(XA[mt][ks], B1, hacc[mt]);
                }
#pragma unroll
                for (int mt = 0; mt < 4; ++mt)
#pragma unroll
                    for (int r = 0; r < 4; ++r)
                        sX[(mt * 16 + quad * 4 + r) * STS + w * 16 + lq] = bfc(fmaxf(hacc[mt][r], 0.f));
            }
            __syncthreads();
            for (int c = 0; c < 16; ++c) {
                short* Hr = (c & 1) ? sPB : sX;          // chunk c lives here
                if (c < 15) {
                    short* Hw = (c & 1) ? sX : sPB;      // chunk c+1 target
                    f32x4 hacc[4];
#pragma unroll
                    for (int mt = 0; mt < 4; ++mt) hacc[mt] = (f32x4){0.f, 0.f, 0.f, 0.f};
#pragma unroll
                    for (int ks = 0; ks < 4; ++ks) {
                        bf16x8 B1 = *(const bf16x8*)&w1p[(size_t)((c + 1) * 128 + w * 16 + lq) * 128 + ks * 32 + quad * 8];
#pragma unroll
                        for (int mt = 0; mt < 4; ++mt) hacc[mt] = MFMA16(XA[mt][ks], B1, hacc[mt]);
                    }
#pragma unroll
                    for (int mt = 0; mt < 4; ++mt)
#pragma unroll
                        for (int r = 0; r < 4; ++r)
                            Hw[(mt * 16 + quad * 4 + r) * STS + w * 16 + lq] = bfc(fmaxf(hacc[mt][r], 0.f));
                }
                // GEMM2(c): wave w -> out cols w*16..+15, accumulate
#pragma unroll
                for (int ks = 0; ks < 4; ++ks) {
                    bf16x8 B2 = *(const bf16x8*)&w2p[(size_t)(w * 16 + lq) * 2048 + c * 128 + ks * 32 + quad * 8];
#pragma unroll
                    for (int mt = 0; mt < 4; ++mt) {
                        bf16x8 A = *(const bf16x8*)&Hr[(mt * 16 + lq) * STS + ks * 32 + quad * 8];
                        yacc[mt] = MFMA16(A, B2, yacc[mt]);
                    }
                }
                __syncthreads();
            }
            // z2 = Y + x
#pragma unroll
            for (int mt = 0; mt < 4; ++mt)
#pragma unroll
                for (int r = 0; r < 4; ++r) {
                    int row = mt * 16 + quad * 4 + r;
                    int col = w * 16 + lq;
                    sT[row * STS + col] = bfc(yacc[mt][r] + b2f(sT[row * STS + col]));
                }
        }
        __syncthreads();

        // ---- t = LN(z2) in place ----
        ln_stats64(sT, tid, 0, sPa, sPb, sMean, sRstd);
        ln_apply64(sT, tid, sMean, sRstd);
    }

    // ================= final single-head attention (d_q = 128) ==============
    // Qf = t @ Wq_f -> sX
    {
        bf16x8 B[4];
#pragma unroll
        for (int ks = 0; ks < 4; ++ks)
            B[ks] = *(const bf16x8*)&WQFT[(w * 16 + lq) * 128 + ks * 32 + quad * 8];
#pragma unroll
        for (int mt = 0; mt < 4; ++mt) {
            f32x4 acc = {0.f, 0.f, 0.f, 0.f};
#pragma unroll
            for (int ks = 0; ks < 4; ++ks) {
                bf16x8 A = *(const bf16x8*)&sT[(mt * 16 + lq) * STS + ks * 32 + quad * 8];
                acc = MFMA16(A, B[ks], acc);
            }
#pragma unroll
            for (int r = 0; r < 4; ++r)
                sX[(mt * 16 + quad * 4 + r) * STS + w * 16 + lq] = bfc(acc[r]);
        }
    }
    // stage kf/vf + score buffer in sPB (dead)
    short* kfL = sPB;
    short* vfL = sPB + 16 * STS;
    float* scF = (float*)(sPB + 2 * 16 * STS);       // [64][17] fp32
    for (int o = tid; o < 2048; o += 512) {
        kfL[(o >> 7) * STS + (o & 127)] = bfc(kf[o]);
        vfL[(o >> 7) * STS + (o & 127)] = bfc(vf[o]);
    }
    __syncthreads();
    // scores[m][k] = Qf[m] . kf[k] / sqrt(128)
    if (tid < 256) {
        int m = tid >> 2, kq = tid & 3;
        float a4[4] = {0.f, 0.f, 0.f, 0.f};
        for (int d8 = 0; d8 < 16; ++d8) {
            bf16x8 qc = *(const bf16x8*)&sX[m * STS + d8 * 8];
            float qf[8];
#pragma unroll
            for (int e = 0; e < 8; ++e) qf[e] = b2f(qc[e]);
#pragma unroll
            for (int k = 0; k < 4; ++k) {
                bf16x8 kc = *(const bf16x8*)&kfL[(kq * 4 + k) * STS + d8 * 8];
#pragma unroll
                for (int e = 0; e < 8; ++e) a4[k] += qf[e] * b2f(kc[e]);
            }
        }
#pragma unroll
        for (int k = 0; k < 4; ++k)
            scF[m * 17 + kq * 4 + k] = a4[k] * 0.08838834764831845f;
    }
    __syncthreads();
    if (tid < 64) {
        float* row = scF + tid * 17;
        float mx = row[0];
#pragma unroll
        for (int k = 1; k < 16; ++k) mx = fmaxf(mx, row[k]);
        float sum = 0.f;
#pragma unroll
        for (int k = 0; k < 16; ++k) { float e = expf(row[k] - mx); row[k] = e; sum += e; }
        float inv = 1.f / sum;
#pragma unroll
        for (int k = 0; k < 16; ++k) row[k] *= inv;
    }
    __syncthreads();
    // z3 = attn @ vf + t -> sX
    {
        int jj = tid & 127, rr0 = tid >> 7;
        float vv[16];
#pragma unroll
        for (int k = 0; k < 16; ++k) vv[k] = b2f(vfL[k * STS + jj]);
#pragma unroll 4
        for (int rr = 0; rr < 16; ++rr) {
            int row = rr0 + 4 * rr;
            float acc = 0.f;
#pragma unroll
            for (int k = 0; k < 16; ++k) acc += scF[row * 17 + k] * vv[k];
            sX[row * STS + jj] = bfc(acc + b2f(sT[row * STS + jj]));
        }
    }
    __syncthreads();
    // out = LN(z3), fp32
    ln_stats64(sX, tid, 0, sPa, sPb, sMean, sRstd);
    for (int o = tid; o < MROWS * 128; o += 512) {
        int r = o >> 7;
        out[(size_t)T0 * 2048 + o] = (b2f(sX[r * STS + (o & 127)]) - sMean[r]) * sRstd[r];
    }
}

extern "C" void kernel_launch(void* const* d_in, const int* in_sizes, int n_in,
                              void* d_out, int out_size, void* d_ws, size_t ws_size,
                              hipStream_t stream) {
    const float* g      = (const float*)d_in[0];
    const float* lf     = (const float*)d_in[1];
    const float* Wvis   = (const float*)d_in[2];
    const float* Wtxt   = (const float*)d_in[3];
    const float* Wq_enc = (const float*)d_in[4];
    const float* Wk_enc = (const float*)d_in[5];
    const float* Wv_enc = (const float*)d_in[6];
    const float* W1f    = (const float*)d_in[7];
    const float* W2f    = (const float*)d_in[8];
    const float* Wqf    = (const float*)d_in[9];
    const float* Wkf    = (const float*)d_in[10];
    const float* Wvf    = (const float*)d_in[11];
    float* out = (float*)d_out;
    float* ws  = (float*)d_ws;

    short* WVH  = (short*)(ws + OFF_WVH);
    short* WVL  = (short*)(ws + OFF_WVL);
    short* WKVH = (short*)(ws + OFF_WKVH);
    short* WKVL = (short*)(ws + OFF_WKVL);
    short* kvB  = (short*)(ws + OFF_KV);
    float* text = ws + OFF_TEXT;
    float* kfp  = ws + OFF_KF;
    float* vfp  = ws + OFF_VF;
    short* W1T  = (short*)(ws + OFF_W1T);
    short* W2T  = (short*)(ws + OFF_W2T);
    short* WQT  = (short*)(ws + OFF_WQT);
    short* WQFT = (short*)(ws + OFF_WQFT);

    // zero only the 63 pad rows at the head of each bf16 K/V array
    for (int a = 0; a < 4; ++a)
        hipMemsetAsync(kvB + (size_t)a * ASTRIDE, 0, (size_t)PAD * DM * sizeof(short), stream);

    k_wcvt <<<dim3(64, 7), dim3(256), 0, stream>>>(Wq_enc, W1f, W2f, Wqf, Wk_enc, Wv_enc, Wvis,
                                                   W1T, W2T, WQT, WQFT, WKVH, WKVL, WVH, WVL);
    k_viskv<<<dim3(TFRAMES / 16), dim3(256), 0, stream>>>(lf, WVH, WVL, WKVH, WKVL, kvB);
    k_text <<<dim3(NG), dim3(128), 0, stream>>>(g, Wtxt, Wkf, Wvf, text, kfp, vfp);
    k_frames<<<dim3(TFRAMES / FPB), dim3(512), 0, stream>>>(kvB, text, kfp, vfp, W1T, W2T, WQT, WQFT, out);
}

// Round 10
// 582.107 us; speedup vs baseline: 1.0368x; 1.0368x over previous
//
#include <hip/hip_runtime.h>
#include <math.h>

#define TFRAMES 4096
#define DM 128
#define LQ 64
#define NG 16
#define NH 8
#define DQH 16
#define FD 2048
#define GFD 512
#define PAD 63
#define KVROWS (TFRAMES + PAD)      /* 4159 */
#define ASTRIDE (KVROWS * DM)       /* 532352 SHORTS per bf16 K/V array */
#define FPB 4                       /* frames per block */
#define MROWS (FPB * NG)            /* 64 state rows per block */
#define STS 136                     /* state row stride (shorts, mult of 8) */
#define VTS 72                      /* V^T row stride (shorts) */
#define PBS 72                      /* P buffer row stride (shorts) */
#define UROWS (LQ + FPB - 1)        /* 67 K/V union rows */

/* ws layout (floats). */
#define OFF_WVH  0                                 /* Wvis^T hi: 128x2048 sh = 131072 fl */
#define OFF_WVL  131072
#define OFF_WKVH 262144                            /* Wk/Wv^T hi: 4x16384 sh = 32768 fl */
#define OFF_WKVL 294912
#define OFF_KV   (TFRAMES * DM)                    /* 524288 */
#define OFF_TEXT (OFF_KV + 2 * ASTRIDE)
#define OFF_KF   (OFF_TEXT + NG * DM)
#define OFF_VF   (OFF_KF + NG * DM)
#define OFF_W1T  (OFF_VF + NG * DM)
#define OFF_W2T  (OFF_W1T + 262144)
#define OFF_WQT  (OFF_W2T + 262144)
#define OFF_WQFT (OFF_WQT + 16384)

typedef __attribute__((ext_vector_type(8))) short bf16x8;
typedef __attribute__((ext_vector_type(4))) float f32x4;
#define MFMA16(a, b, c) __builtin_amdgcn_mfma_f32_16x16x32_bf16(a, b, c, 0, 0, 0)

// f32->bf16 RNE via the compiler's native __bf16 cast (r8-verified: PASS,
// VALUBusy 38->33%, dur 442->432; bit-identical absmax).
__device__ __forceinline__ short bfc(float x) {
    union { __bf16 b; short s; } v;
    v.b = (__bf16)x;
    return v.s;
}
__device__ __forceinline__ float b2f(short s) {
    union { unsigned u; float f; } v;
    v.u = ((unsigned)(unsigned short)s) << 16;
    return v.f;
}
// Extract 8 shorts starting at short-offset f (0..3) from the 12-short window
// {a.x..a.w, b.x, b.y}. v_alignbit_b32 shift is 5-bit (wraps at 32!), so split
// f into a word offset (wo = f>>1, uniform select) + residual 0/16-bit shift.
__device__ __forceinline__ bf16x8 shiftf(int4 a, int4 b, int f) {
    const int wo = f >> 1;
    const int sh = (f & 1) * 16;
    int w0 = wo ? a.y : a.x;
    int w1 = wo ? a.z : a.y;
    int w2 = wo ? a.w : a.z;
    int w3 = wo ? b.x : a.w;
    int w4 = wo ? b.y : b.x;
    int o0 = __builtin_amdgcn_alignbit(w1, w0, sh);
    int o1 = __builtin_amdgcn_alignbit(w2, w1, sh);
    int o2 = __builtin_amdgcn_alignbit(w3, w2, sh);
    int o3 = __builtin_amdgcn_alignbit(w4, w3, sh);
    int4 o = {o0, o1, o2, o3};
    return *(bf16x8*)&o;
}

// -------- kernel W: unified coalesced LDS tile-transpose of all weights ------
__global__ __launch_bounds__(256) void k_wcvt(const float* __restrict__ Wq_enc,
                                              const float* __restrict__ W1f,
                                              const float* __restrict__ W2f,
                                              const float* __restrict__ Wqf,
                                              const float* __restrict__ Wk_enc,
                                              const float* __restrict__ Wv_enc,
                                              const float* __restrict__ Wvis,
                                              short* __restrict__ W1T,
                                              short* __restrict__ W2T,
                                              short* __restrict__ WQT,
                                              short* __restrict__ WQFT,
                                              short* __restrict__ WKVH,
                                              short* __restrict__ WKVL,
                                              short* __restrict__ WVH,
                                              short* __restrict__ WVL) {
    __shared__ float tile[64][65];
    const int tid = threadIdx.x;
    const int gy = blockIdx.y, gx = blockIdx.x;
    const float* src; short* dst; short* dstL = nullptr;
    int sstride, dstride, tr, tc;
    if (gy < 2) {            // W1: [128][2048] -> W1T [2048][128]
        src = W1f + (size_t)gy * 262144; dst = W1T + gy * 262144;
        sstride = 2048; dstride = 128; tr = gx >> 5; tc = gx & 31;
    } else if (gy < 4) {     // W2: [2048][128] -> W2T [128][2048]
        int l = gy - 2;
        src = W2f + (size_t)l * 262144; dst = W2T + l * 262144;
        sstride = 128; dstride = 2048; tr = gx >> 1; tc = gx & 1;
    } else if (gy == 4) {    // WQ l0,l1, WQF: [128][128]
        if (gx >= 12) return;
        int t = gx >> 2;
        src = (t < 2) ? Wq_enc + (size_t)t * 16384 : Wqf;
        dst = (t < 2) ? WQT + t * 16384 : WQFT;
        sstride = 128; dstride = 128; tr = (gx >> 1) & 1; tc = gx & 1;
    } else if (gy == 5) {    // WKV hi/lo: a = 2l + isV
        if (gx >= 16) return;
        int a = gx >> 2;
        src = ((a & 1) ? Wv_enc : Wk_enc) + (size_t)(a >> 1) * 16384;
        dst = WKVH + a * 16384; dstL = WKVL + a * 16384;
        sstride = 128; dstride = 128; tr = (gx >> 1) & 1; tc = gx & 1;
    } else {                 // Wvis: [2048][128] -> WVH/WVL [128][2048]
        src = Wvis; dst = WVH; dstL = WVL;
        sstride = 128; dstride = 2048; tr = gx >> 1; tc = gx & 1;
    }
    const int rb = tr * 64, cb = tc * 64;
    for (int o = tid; o < 64 * 64; o += 256) {
        int r = o >> 6, c = o & 63;
        tile[r][c] = src[(size_t)(rb + r) * sstride + cb + c];
    }
    __syncthreads();
    for (int o = tid; o < 64 * 64; o += 256) {
        int rn = o >> 6, ck = o & 63;
        float v = tile[ck][rn];
        short hi = bfc(v);
        size_t di = (size_t)(cb + rn) * dstride + rb + ck;
        dst[di] = hi;
        if (dstL) dstL[di] = bfc(v - b2f(hi));
    }
}

// -------- kernel P: visual=lf@Wvis, LN, K/V=visn@Wk/Wv — all MFMA, hi/lo -----
// 3-pass hi/lo (AhBh + AlBh + AhBl) keeps ~fp32 accuracy end to end.
// r10: 512 threads / 8 waves (was 256/4 = 12.5% occupancy, latency-bound).
// Wave w now owns 16 out cols (nt loop gone): serial MFMA chain per wave
// halves; per-element accumulation sequences and the LN partial-sum tree
// are unchanged -> bit-identical output.
__global__ __launch_bounds__(512) void k_viskv(const float* __restrict__ lf,
                                               const short* __restrict__ WVH,
                                               const short* __restrict__ WVL,
                                               const short* __restrict__ WKVH,
                                               const short* __restrict__ WKVL,
                                               short* __restrict__ kvB) {
    __shared__ __align__(16) char smem[17408 + 4352];   // Ah|Al  /  vis | Vh | Vl
    __shared__ float sPa[256], sPb[256], sMean[16], sRstd[16];
    short* Ah = (short*)smem;                 // [16][136] bf16 (4352 B)
    short* Al = (short*)(smem + 4352);        // [16][136]
    float* vis = (float*)smem;                // [16][132] fp32 (8448 B, overlays Ah/Al)
    short* Vh = (short*)(smem + 8704);        // [16][136]
    short* Vl = (short*)(smem + 13056);       // [16][136]

    const int tid = threadIdx.x;              // 512 = 8 waves
    const int w = tid >> 6;                   // wave 0..7 -> out cols w*16..+15
    const int lane = tid & 63;
    const int lq = lane & 15;
    const int quad = lane >> 4;
    const int r0 = blockIdx.x * 16;           // 256 blocks x 16 rows

    // ---- phase 1: visual = lf @ Wvis  (K=2048 in 16 chunks of 128) ----
    f32x4 acc = {0.f, 0.f, 0.f, 0.f};         // wave w -> out cols w*16..+15
    for (int c = 0; c < 16; ++c) {
        __syncthreads();                      // prior MFMA reads done before overwrite
        for (int o = tid; o < 16 * 128; o += 512) {
            int r = o >> 7, j = o & 127;
            float v = lf[(size_t)(r0 + r) * FD + c * 128 + j];
            short hi = bfc(v);
            Ah[r * 136 + j] = hi;
            Al[r * 136 + j] = bfc(v - b2f(hi));
        }
        __syncthreads();
#pragma unroll
        for (int ks = 0; ks < 4; ++ks) {
            bf16x8 ah = *(const bf16x8*)&Ah[lq * 136 + ks * 32 + quad * 8];
            bf16x8 al = *(const bf16x8*)&Al[lq * 136 + ks * 32 + quad * 8];
            const size_t bo = (size_t)(w * 16 + lq) * FD + c * 128 + ks * 32 + quad * 8;
            bf16x8 bh = *(const bf16x8*)&WVH[bo];
            bf16x8 bl = *(const bf16x8*)&WVL[bo];
            acc = MFMA16(ah, bh, acc);
            acc = MFMA16(al, bh, acc);
            acc = MFMA16(ah, bl, acc);
        }
    }
    __syncthreads();
    // C-layout -> vis[row][col] fp32 (row = quad*4+r, col = w*16+lq)
#pragma unroll
    for (int r = 0; r < 4; ++r)
        vis[(quad * 4 + r) * 132 + w * 16 + lq] = acc[r];
    __syncthreads();

    // ---- phase 2: LN over 128 cols per row (exact 256-thread tree kept
    //      for bit-identical stats; threads >=256 idle here) ----
    if (tid < 256) {
        int row = tid >> 4, p = tid & 15;     // 8 cols per thread
        float s = 0.f, s2 = 0.f;
#pragma unroll
        for (int k = 0; k < 8; ++k) { float v = vis[row * 132 + p * 8 + k]; s += v; s2 += v * v; }
        sPa[tid] = s; sPb[tid] = s2;
    }
    __syncthreads();
    if (tid < 16) {
        float s = 0.f, s2 = 0.f;
#pragma unroll
        for (int p = 0; p < 16; ++p) { s += sPa[tid * 16 + p]; s2 += sPb[tid * 16 + p]; }
        float m = s * (1.f / 128.f);
        float v = s2 * (1.f / 128.f) - m * m;
        sMean[tid] = m; sRstd[tid] = rsqrtf(v + 1e-5f);
    }
    __syncthreads();
    for (int o = tid; o < 16 * 128; o += 512) {
        int r = o >> 7, j = o & 127;
        float v = (vis[r * 132 + j] - sMean[r]) * sRstd[r];
        short hi = bfc(v);
        Vh[r * 136 + j] = hi;
        Vl[r * 136 + j] = bfc(v - b2f(hi));
    }
    __syncthreads();

    // ---- phase 3: K/V = visn @ Wk/Wv per array (K=128), bf16 out ----
    for (int a = 0; a < 4; ++a) {
        f32x4 ka = {0.f, 0.f, 0.f, 0.f};
#pragma unroll
        for (int ks = 0; ks < 4; ++ks) {
            bf16x8 ah = *(const bf16x8*)&Vh[lq * 136 + ks * 32 + quad * 8];
            bf16x8 al = *(const bf16x8*)&Vl[lq * 136 + ks * 32 + quad * 8];
            const size_t bo = (size_t)a * 16384 + (size_t)(w * 16 + lq) * 128 + ks * 32 + quad * 8;
            bf16x8 bh = *(const bf16x8*)&WKVH[bo];
            bf16x8 bl = *(const bf16x8*)&WKVL[bo];
            ka = MFMA16(ah, bh, ka);
            ka = MFMA16(al, bh, ka);
            ka = MFMA16(ah, bl, ka);
        }
#pragma unroll
        for (int r = 0; r < 4; ++r)
            kvB[(size_t)a * ASTRIDE + (size_t)(PAD + r0 + quad * 4 + r) * DM + w * 16 + lq]
                = bfc(ka[r]);
    }
}

// -------- kernel 3: text = g @ W_txt ; Kf = text @ Wk_f ; Vf = text @ Wv_f ---
__global__ __launch_bounds__(128) void k_text(const float* __restrict__ g,
                                              const float* __restrict__ Wtxt,
                                              const float* __restrict__ Wkf,
                                              const float* __restrict__ Wvf,
                                              float* __restrict__ text,
                                              float* __restrict__ kf,
                                              float* __restrict__ vf) {
    __shared__ float gs[GFD];
    __shared__ float tr[DM];
    const int r = blockIdx.x;
    const int tid = threadIdx.x;
    for (int i = tid; i < GFD; i += 128) gs[i] = g[(size_t)r * GFD + i];
    __syncthreads();
    float acc = 0.f;
    for (int k = 0; k < GFD; ++k) acc += gs[k] * Wtxt[(size_t)k * DM + tid];
    tr[tid] = acc;
    text[(size_t)r * DM + tid] = acc;
    __syncthreads();
    float a1 = 0.f, a2 = 0.f;
    for (int k = 0; k < DM; ++k) {
        float x = tr[k];
        a1 += x * Wkf[(size_t)k * DM + tid];
        a2 += x * Wvf[(size_t)k * DM + tid];
    }
    kf[(size_t)r * DM + tid] = a1;
    vf[(size_t)r * DM + tid] = a2;
}

// ---------------- LN helpers for [64][STS] bf16 LDS tile ---------------------
__device__ __forceinline__ void ln_stats64(const short* buf, int tid, int dbl,
                                           float* pa, float* pb, float* ms, float* rs) {
    {
        int row = tid >> 3, p = tid & 7;
        const bf16x8* bp = (const bf16x8*)(buf + row * STS + p * 16);
        float s = 0.f, s2 = 0.f;
#pragma unroll
        for (int q8 = 0; q8 < 2; ++q8) {
            bf16x8 x = bp[q8];
#pragma unroll
            for (int e = 0; e < 8; ++e) { float v = b2f(x[e]); s += v; s2 += v * v; }
        }
        pa[tid] = s; pb[tid] = s2;
    }
    __syncthreads();
    if (tid < 64) {
        float ss = 0.f, ss2 = 0.f;
#pragma unroll
        for (int p2 = 0; p2 < 8; ++p2) { ss += pa[tid * 8 + p2]; ss2 += pb[tid * 8 + p2]; }
        float m = ss * (1.f / 128.f);
        float v = ss2 * (1.f / 128.f) - m * m;
        float r = rsqrtf(v + 1e-5f);
        if (dbl) r *= rsqrtf(v / (v + 1e-5f) + 1e-5f);   // exact LN(LN(x)) fold
        ms[tid] = m; rs[tid] = r;
    }
    __syncthreads();
}
__device__ __forceinline__ void ln_apply64(short* buf, int tid,
                                           const float* ms, const float* rs) {
    int row = tid >> 3, p = tid & 7;
    float m = ms[row], r = rs[row];
    bf16x8* bp = (bf16x8*)(buf + row * STS + p * 16);
#pragma unroll
    for (int q8 = 0; q8 < 2; ++q8) {
        bf16x8 x = bp[q8]; bf16x8 o;
#pragma unroll
        for (int e = 0; e < 8; ++e) o[e] = bfc((b2f(x[e]) - m) * r);
        bp[q8] = o;
    }
    __syncthreads();
}

// ---------------- kernel 4: 4 frames/block, MFMA attention + FFN -------------
__global__ __launch_bounds__(512, 4) void k_frames(
    const short* __restrict__ kvB,    const float* __restrict__ text,
    const float* __restrict__ kf,     const float* __restrict__ vf,
    const short* __restrict__ W1T,    const short* __restrict__ W2T,
    const short* __restrict__ WQT,    const short* __restrict__ WQFT,
    float* __restrict__ out) {
    __shared__ __align__(16) short sT[MROWS * STS];     // state (t / z / x / z2)
    __shared__ __align__(16) short sX[MROWS * STS];     // Q / H-chunk / Qf / z3
    __shared__ __align__(16) short sVT[128 * VTS];      // V^T union (dims x keys)
    __shared__ __align__(16) short sPB[8 * 16 * PBS];   // per-wave P; FFN H dbuf; kf/vf/scores
    __shared__ float sPa[512], sPb[512];
    __shared__ float sMean[64], sRstd[64];

    const int tid = threadIdx.x;        // 512 = 8 waves
    const int w = tid >> 6;             // wave 0..7
    const int lane = tid & 63;
    const int lq = lane & 15;
    const int quad = lane >> 4;
    // XCD-aware swizzle (T1): keeps each XCD on a contiguous frame chunk
    // (FETCH 115->99 MB verified r0->r6; time-neutral but strictly less HBM).
    const int bswz = (blockIdx.x & 7) * 128 + (blockIdx.x >> 3);
    const int T0 = bswz * FPB;

    // init: t rows m = f*16+q <- text[q][:]
    for (int o = tid; o < MROWS * 128; o += 512)
        sT[(o >> 7) * STS + (o & 127)] = bfc(text[((o >> 7) & 15) * 128 + (o & 127)]);
    __syncthreads();

    for (int l = 0; l < 2; ++l) {
        const short* kvK = kvB + (size_t)(2 * l) * ASTRIDE;
        const short* kvV = kvB + (size_t)(2 * l + 1) * ASTRIDE;

        // ---- stage V^T union (coalesced; barrier inside ln_stats covers it) --
        for (int o = tid; o < UROWS * 128; o += 512) {
            int u = o >> 7, d = o & 127;
            sVT[d * VTS + u] = kvV[(size_t)(T0 + u) * 128 + d];
        }
        ln_stats64(sT, tid, 0, sPa, sPb, sMean, sRstd);

        // ---- Q = LN(t) @ Wq[l] -> sX (LN applied inline on A-fragments) ----
        {
            const short* wq = WQT + (size_t)l * 16384;
            bf16x8 B[4];
#pragma unroll
            for (int ks = 0; ks < 4; ++ks)
                B[ks] = *(const bf16x8*)&wq[(w * 16 + lq) * 128 + ks * 32 + quad * 8];
#pragma unroll
            for (int mt = 0; mt < 4; ++mt) {
                int row = mt * 16 + lq;
                float m = sMean[row], r = sRstd[row];
                f32x4 acc = {0.f, 0.f, 0.f, 0.f};
#pragma unroll
                for (int ks = 0; ks < 4; ++ks) {
                    bf16x8 t8 = *(const bf16x8*)&sT[row * STS + ks * 32 + quad * 8];
                    bf16x8 a8;
#pragma unroll
                    for (int e = 0; e < 8; ++e) a8[e] = bfc((b2f(t8[e]) - m) * r);
                    acc = MFMA16(a8, B[ks], acc);
                }
#pragma unroll
                for (int r4 = 0; r4 < 4; ++r4)
                    sX[(mt * 16 + quad * 4 + r4) * STS + w * 16 + lq] = bfc(acc[r4]);
            }
        }
        __syncthreads();

        // ---- attention: wave pair (2f, 2f+1) handles frame f, 4 heads each --
        {
            const int f = w >> 1;
            const int hg = (w & 1) * 4;
            short* Pb = sPB + w * 16 * PBS;
            bf16x8 zv = {};
            for (int hh = 0; hh < 4; ++hh) {
                const int h = hg + hh;
                bf16x8 aq;
                {
                    bf16x8 t8 = *(const bf16x8*)&sX[(f * 16 + lq) * STS + h * 16 + (quad & 1) * 8];
                    aq = (quad < 2) ? t8 : zv;
                }
                f32x4 sc4[4];
#pragma unroll
                for (int kt = 0; kt < 4; ++kt) {
                    bf16x8 bk = *(const bf16x8*)&kvK[(size_t)(T0 + f + kt * 16 + lq) * 128 + h * 16 + (quad & 1) * 8];
                    bk = (quad < 2) ? bk : zv;
                    f32x4 z4 = {0.f, 0.f, 0.f, 0.f};
                    sc4[kt] = MFMA16(aq, bk, z4);
                }
                // softmax in C-layout registers; keep fp32 P values
                float pr[4][4];   // [r][kt]
#pragma unroll
                for (int r = 0; r < 4; ++r) {
                    float a0 = sc4[0][r] * 0.25f, a1 = sc4[1][r] * 0.25f;
                    float a2 = sc4[2][r] * 0.25f, a3 = sc4[3][r] * 0.25f;
                    float mx = fmaxf(fmaxf(a0, a1), fmaxf(a2, a3));
                    mx = fmaxf(mx, __shfl_xor(mx, 1));
                    mx = fmaxf(mx, __shfl_xor(mx, 2));
                    mx = fmaxf(mx, __shfl_xor(mx, 4));
                    mx = fmaxf(mx, __shfl_xor(mx, 8));
                    float e0 = expf(a0 - mx), e1 = expf(a1 - mx);
                    float e2 = expf(a2 - mx), e3 = expf(a3 - mx);
                    float s = e0 + e1 + e2 + e3;
                    s += __shfl_xor(s, 1);
                    s += __shfl_xor(s, 2);
                    s += __shfl_xor(s, 4);
                    s += __shfl_xor(s, 8);
                    float inv = 1.f / s;
                    pr[r][0] = e0 * inv; pr[r][1] = e1 * inv;
                    pr[r][2] = e2 * inv; pr[r][3] = e3 * inv;
                }
                // V^T window fragments once (register-resident across hi/lo passes)
                const short* vr = &sVT[(h * 16 + lq) * VTS];
                int4 v0 = *(const int4*)&vr[quad * 8];
                int4 v1 = *(const int4*)&vr[quad * 8 + 8];
                int4 u0 = *(const int4*)&vr[32 + quad * 8];
                int4 u1 = *(const int4*)&vr[32 + quad * 8 + 8];
                bf16x8 b0 = shiftf(v0, v1, f);
                bf16x8 b1 = shiftf(u0, u1, f);
                // PV with hi+lo bf16 split of P (extra precision margin).
                f32x4 ctx = {0.f, 0.f, 0.f, 0.f};
#pragma unroll
                for (int pass = 0; pass < 2; ++pass) {
#pragma unroll
                    for (int r = 0; r < 4; ++r)
#pragma unroll
                        for (int kt = 0; kt < 4; ++kt) {
                            float p = pr[r][kt];
                            short hi = bfc(p);
                            short v16 = pass == 0 ? hi : bfc(p - b2f(hi));
                            Pb[(quad * 4 + r) * PBS + kt * 16 + lq] = v16;
                        }
                    bf16x8 p0 = *(const bf16x8*)&Pb[lq * PBS + quad * 8];
                    bf16x8 p1 = *(const bf16x8*)&Pb[lq * PBS + 32 + quad * 8];
                    ctx = MFMA16(p0, b0, ctx);
                    ctx = MFMA16(p1, b1, ctx);
                }
                // z = ctx + tq  (tq recomputed from t + stats, fp32)
#pragma unroll
                for (int r = 0; r < 4; ++r) {
                    int row = f * 16 + quad * 4 + r;
                    int col = h * 16 + lq;
                    float tq = (b2f(sT[row * STS + col]) - sMean[row]) * sRstd[row];
                    sT[row * STS + col] = bfc(ctx[r] + tq);
                }
            }
        }
        __syncthreads();

        // ---- x = LN(LN(z)) in place ----
        ln_stats64(sT, tid, 1, sPa, sPb, sMean, sRstd);
        ln_apply64(sT, tid, sMean, sRstd);

        // ---- FFN: z2 = relu(x@W1)@W2 + x -> sT ----
        // H-chunk double-buffered through sX / sPB (r9: -4us, kept).
        {
            const short* w1p = W1T + (size_t)l * 262144;
            const short* w2p = W2T + (size_t)l * 262144;
            bf16x8 XA[4][4];
#pragma unroll
            for (int mt = 0; mt < 4; ++mt)
#pragma unroll
                for (int ks = 0; ks < 4; ++ks)
                    XA[mt][ks] = *(const bf16x8*)&sT[(mt * 16 + lq) * STS + ks * 32 + quad * 8];
            f32x4 yacc[4];
#pragma unroll
            for (int mt = 0; mt < 4; ++mt) yacc[mt] = (f32x4){0.f, 0.f, 0.f, 0.f};
            // prologue: GEMM1 chunk 0 -> sX (buffer 0)
            {
                f32x4 hacc[4];
#pragma unroll
                for (int mt = 0; mt < 4; ++mt) hacc[mt] = (f32x4){0.f, 0.f, 0.f, 0.f};
#pragma unroll
                for (int ks = 0; ks < 4; ++ks) {
                    bf16x8 B1 = *(const bf16x8*)&w1p[(size_t)(w * 16 + lq) * 128 + ks * 32 + quad * 8];
#pragma unroll
                    for (int mt = 0; mt < 4; ++mt) hacc[mt] = MFMA16(XA[mt][ks], B1, hacc[mt]);
                }
#pragma unroll
                for (int mt = 0; mt < 4; ++mt)
#pragma unroll
                    for (int r = 0; r < 4; ++r)
                        sX[(mt * 16 + quad * 4 + r) * STS + w * 16 + lq] = bfc(fmaxf(hacc[mt][r], 0.f));
            }
            __syncthreads();
            for (int c = 0; c < 16; ++c) {
                short* Hr = (c & 1) ? sPB : sX;          // chunk c lives here
                if (c < 15) {
                    short* Hw = (c & 1) ? sX : sPB;      // chunk c+1 target
                    f32x4 hacc[4];
#pragma unroll
                    for (int mt = 0; mt < 4; ++mt) hacc[mt] = (f32x4){0.f, 0.f, 0.f, 0.f};
#pragma unroll
                    for (int ks = 0; ks < 4; ++ks) {
                        bf16x8 B1 = *(const bf16x8*)&w1p[(size_t)((c + 1) * 128 + w * 16 + lq) * 128 + ks * 32 + quad * 8];
#pragma unroll
                        for (int mt = 0; mt < 4; ++mt) hacc[mt] = MFMA16(XA[mt][ks], B1, hacc[mt]);
                    }
#pragma unroll
                    for (int mt = 0; mt < 4; ++mt)
#pragma unroll
                        for (int r = 0; r < 4; ++r)
                            Hw[(mt * 16 + quad * 4 + r) * STS + w * 16 + lq] = bfc(fmaxf(hacc[mt][r], 0.f));
                }
                // GEMM2(c): wave w -> out cols w*16..+15, accumulate
#pragma unroll
                for (int ks = 0; ks < 4; ++ks) {
                    bf16x8 B2 = *(const bf16x8*)&w2p[(size_t)(w * 16 + lq) * 2048 + c * 128 + ks * 32 + quad * 8];
#pragma unroll
                    for (int mt = 0; mt < 4; ++mt) {
                        bf16x8 A = *(const bf16x8*)&Hr[(mt * 16 + lq) * STS + ks * 32 + quad * 8];
                        yacc[mt] = MFMA16(A, B2, yacc[mt]);
                    }
                }
                __syncthreads();
            }
            // z2 = Y + x
#pragma unroll
            for (int mt = 0; mt < 4; ++mt)
#pragma unroll
                for (int r = 0; r < 4; ++r) {
                    int row = mt * 16 + quad * 4 + r;
                    int col = w * 16 + lq;
                    sT[row * STS + col] = bfc(yacc[mt][r] + b2f(sT[row * STS + col]));
                }
        }
        __syncthreads();

        // ---- t = LN(z2) in place ----
        ln_stats64(sT, tid, 0, sPa, sPb, sMean, sRstd);
        ln_apply64(sT, tid, sMean, sRstd);
    }

    // ================= final single-head attention (d_q = 128) ==============
    // Qf = t @ Wq_f -> sX
    {
        bf16x8 B[4];
#pragma unroll
        for (int ks = 0; ks < 4; ++ks)
            B[ks] = *(const bf16x8*)&WQFT[(w * 16 + lq) * 128 + ks * 32 + quad * 8];
#pragma unroll
        for (int mt = 0; mt < 4; ++mt) {
            f32x4 acc = {0.f, 0.f, 0.f, 0.f};
#pragma unroll
            for (int ks = 0; ks < 4; ++ks) {
                bf16x8 A = *(const bf16x8*)&sT[(mt * 16 + lq) * STS + ks * 32 + quad * 8];
                acc = MFMA16(A, B[ks], acc);
            }
#pragma unroll
            for (int r = 0; r < 4; ++r)
                sX[(mt * 16 + quad * 4 + r) * STS + w * 16 + lq] = bfc(acc[r]);
        }
    }
    // stage kf/vf + score buffer in sPB (dead)
    short* kfL = sPB;
    short* vfL = sPB + 16 * STS;
    float* scF = (float*)(sPB + 2 * 16 * STS);       // [64][17] fp32
    for (int o = tid; o < 2048; o += 512) {
        kfL[(o >> 7) * STS + (o & 127)] = bfc(kf[o]);
        vfL[(o >> 7) * STS + (o & 127)] = bfc(vf[o]);
    }
    __syncthreads();
    // scores[m][k] = Qf[m] . kf[k] / sqrt(128)
    if (tid < 256) {
        int m = tid >> 2, kq = tid & 3;
        float a4[4] = {0.f, 0.f, 0.f, 0.f};
        for (int d8 = 0; d8 < 16; ++d8) {
            bf16x8 qc = *(const bf16x8*)&sX[m * STS + d8 * 8];
            float qf[8];
#pragma unroll
            for (int e = 0; e < 8; ++e) qf[e] = b2f(qc[e]);
#pragma unroll
            for (int k = 0; k < 4; ++k) {
                bf16x8 kc = *(const bf16x8*)&kfL[(kq * 4 + k) * STS + d8 * 8];
#pragma unroll
                for (int e = 0; e < 8; ++e) a4[k] += qf[e] * b2f(kc[e]);
            }
        }
#pragma unroll
        for (int k = 0; k < 4; ++k)
            scF[m * 17 + kq * 4 + k] = a4[k] * 0.08838834764831845f;
    }
    __syncthreads();
    if (tid < 64) {
        float* row = scF + tid * 17;
        float mx = row[0];
#pragma unroll
        for (int k = 1; k < 16; ++k) mx = fmaxf(mx, row[k]);
        float sum = 0.f;
#pragma unroll
        for (int k = 0; k < 16; ++k) { float e = expf(row[k] - mx); row[k] = e; sum += e; }
        float inv = 1.f / sum;
#pragma unroll
        for (int k = 0; k < 16; ++k) row[k] *= inv;
    }
    __syncthreads();
    // z3 = attn @ vf + t -> sX
    {
        int jj = tid & 127, rr0 = tid >> 7;
        float vv[16];
#pragma unroll
        for (int k = 0; k < 16; ++k) vv[k] = b2f(vfL[k * STS + jj]);
#pragma unroll 4
        for (int rr = 0; rr < 16; ++rr) {
            int row = rr0 + 4 * rr;
            float acc = 0.f;
#pragma unroll
            for (int k = 0; k < 16; ++k) acc += scF[row * 17 + k] * vv[k];
            sX[row * STS + jj] = bfc(acc + b2f(sT[row * STS + jj]));
        }
    }
    __syncthreads();
    // out = LN(z3), fp32
    ln_stats64(sX, tid, 0, sPa, sPb, sMean, sRstd);
    for (int o = tid; o < MROWS * 128; o += 512) {
        int r = o >> 7;
        out[(size_t)T0 * 2048 + o] = (b2f(sX[r * STS + (o & 127)]) - sMean[r]) * sRstd[r];
    }
}

extern "C" void kernel_launch(void* const* d_in, const int* in_sizes, int n_in,
                              void* d_out, int out_size, void* d_ws, size_t ws_size,
                              hipStream_t stream) {
    const float* g      = (const float*)d_in[0];
    const float* lf     = (const float*)d_in[1];
    const float* Wvis   = (const float*)d_in[2];
    const float* Wtxt   = (const float*)d_in[3];
    const float* Wq_enc = (const float*)d_in[4];
    const float* Wk_enc = (const float*)d_in[5];
    const float* Wv_enc = (const float*)d_in[6];
    const float* W1f    = (const float*)d_in[7];
    const float* W2f    = (const float*)d_in[8];
    const float* Wqf    = (const float*)d_in[9];
    const float* Wkf    = (const float*)d_in[10];
    const float* Wvf    = (const float*)d_in[11];
    float* out = (float*)d_out;
    float* ws  = (float*)d_ws;

    short* WVH  = (short*)(ws + OFF_WVH);
    short* WVL  = (short*)(ws + OFF_WVL);
    short* WKVH = (short*)(ws + OFF_WKVH);
    short* WKVL = (short*)(ws + OFF_WKVL);
    short* kvB  = (short*)(ws + OFF_KV);
    float* text = ws + OFF_TEXT;
    float* kfp  = ws + OFF_KF;
    float* vfp  = ws + OFF_VF;
    short* W1T  = (short*)(ws + OFF_W1T);
    short* W2T  = (short*)(ws + OFF_W2T);
    short* WQT  = (short*)(ws + OFF_WQT);
    short* WQFT = (short*)(ws + OFF_WQFT);

    // zero only the 63 pad rows at the head of each bf16 K/V array
    for (int a = 0; a < 4; ++a)
        hipMemsetAsync(kvB + (size_t)a * ASTRIDE, 0, (size_t)PAD * DM * sizeof(short), stream);

    k_wcvt <<<dim3(64, 7), dim3(256), 0, stream>>>(Wq_enc, W1f, W2f, Wqf, Wk_enc, Wv_enc, Wvis,
                                                   W1T, W2T, WQT, WQFT, WKVH, WKVL, WVH, WVL);
    k_viskv<<<dim3(TFRAMES / 16), dim3(512), 0, stream>>>(lf, WVH, WVL, WKVH, WKVL, kvB);
    k_text <<<dim3(NG), dim3(128), 0, stream>>>(g, Wtxt, Wkf, Wvf, text, kfp, vfp);
    k_frames<<<dim3(TFRAMES / FPB), dim3(512), 0, stream>>>(kvB, text, kfp, vfp, W1T, W2T, WQT, WQFT, out);
}

// Round 11
// 570.619 us; speedup vs baseline: 1.0576x; 1.0201x over previous
//
#include <hip/hip_runtime.h>
#include <math.h>

#define TFRAMES 4096
#define DM 128
#define LQ 64
#define NG 16
#define NH 8
#define DQH 16
#define FD 2048
#define GFD 512
#define PAD 63
#define KVROWS (TFRAMES + PAD)      /* 4159 */
#define ASTRIDE (KVROWS * DM)       /* 532352 SHORTS per bf16 K/V array */
#define FPB 4                       /* frames per block */
#define MROWS (FPB * NG)            /* 64 state rows per block */
#define STS 136                     /* state row stride (shorts, mult of 8) */
#define VTS 72                      /* V^T row stride (shorts) */
#define PBS 72                      /* P buffer row stride (shorts) */
#define UROWS (LQ + FPB - 1)        /* 67 K/V union rows */

/* ws layout (floats). */
#define OFF_WVH  0                                 /* Wvis^T hi: 128x2048 sh = 131072 fl */
#define OFF_WVL  131072
#define OFF_WKVH 262144                            /* Wk/Wv^T hi: 4x16384 sh = 32768 fl */
#define OFF_WKVL 294912
#define OFF_KV   (TFRAMES * DM)                    /* 524288 */
#define OFF_TEXT (OFF_KV + 2 * ASTRIDE)
#define OFF_KF   (OFF_TEXT + NG * DM)
#define OFF_VF   (OFF_KF + NG * DM)
#define OFF_W1T  (OFF_VF + NG * DM)
#define OFF_W2T  (OFF_W1T + 262144)
#define OFF_WQT  (OFF_W2T + 262144)
#define OFF_WQFT (OFF_WQT + 16384)

typedef __attribute__((ext_vector_type(8))) short bf16x8;
typedef __attribute__((ext_vector_type(4))) short s16x4;
typedef __attribute__((ext_vector_type(4))) float f32x4;
#define MFMA16(a, b, c) __builtin_amdgcn_mfma_f32_16x16x32_bf16(a, b, c, 0, 0, 0)

// f32->bf16 RNE via the compiler's native __bf16 cast (r8-verified: PASS,
// VALUBusy 38->33%, dur 442->432; bit-identical absmax).
__device__ __forceinline__ short bfc(float x) {
    union { __bf16 b; short s; } v;
    v.b = (__bf16)x;
    return v.s;
}
__device__ __forceinline__ float b2f(short s) {
    union { unsigned u; float f; } v;
    v.u = ((unsigned)(unsigned short)s) << 16;
    return v.f;
}
// Extract 8 shorts starting at short-offset f (0..3) from the 12-short window
// {a.x..a.w, b.x, b.y}. v_alignbit_b32 shift is 5-bit (wraps at 32!), so split
// f into a word offset (wo = f>>1, uniform select) + residual 0/16-bit shift.
__device__ __forceinline__ bf16x8 shiftf(int4 a, int4 b, int f) {
    const int wo = f >> 1;
    const int sh = (f & 1) * 16;
    int w0 = wo ? a.y : a.x;
    int w1 = wo ? a.z : a.y;
    int w2 = wo ? a.w : a.z;
    int w3 = wo ? b.x : a.w;
    int w4 = wo ? b.y : b.x;
    int o0 = __builtin_amdgcn_alignbit(w1, w0, sh);
    int o1 = __builtin_amdgcn_alignbit(w2, w1, sh);
    int o2 = __builtin_amdgcn_alignbit(w3, w2, sh);
    int o3 = __builtin_amdgcn_alignbit(w4, w3, sh);
    int4 o = {o0, o1, o2, o3};
    return *(bf16x8*)&o;
}

// -------- kernel W: unified coalesced LDS tile-transpose of all weights ------
__global__ __launch_bounds__(256) void k_wcvt(const float* __restrict__ Wq_enc,
                                              const float* __restrict__ W1f,
                                              const float* __restrict__ W2f,
                                              const float* __restrict__ Wqf,
                                              const float* __restrict__ Wk_enc,
                                              const float* __restrict__ Wv_enc,
                                              const float* __restrict__ Wvis,
                                              short* __restrict__ W1T,
                                              short* __restrict__ W2T,
                                              short* __restrict__ WQT,
                                              short* __restrict__ WQFT,
                                              short* __restrict__ WKVH,
                                              short* __restrict__ WKVL,
                                              short* __restrict__ WVH,
                                              short* __restrict__ WVL) {
    __shared__ float tile[64][65];
    const int tid = threadIdx.x;
    const int gy = blockIdx.y, gx = blockIdx.x;
    const float* src; short* dst; short* dstL = nullptr;
    int sstride, dstride, tr, tc;
    if (gy < 2) {            // W1: [128][2048] -> W1T [2048][128]
        src = W1f + (size_t)gy * 262144; dst = W1T + gy * 262144;
        sstride = 2048; dstride = 128; tr = gx >> 5; tc = gx & 31;
    } else if (gy < 4) {     // W2: [2048][128] -> W2T [128][2048]
        int l = gy - 2;
        src = W2f + (size_t)l * 262144; dst = W2T + l * 262144;
        sstride = 128; dstride = 2048; tr = gx >> 1; tc = gx & 1;
    } else if (gy == 4) {    // WQ l0,l1, WQF: [128][128]
        if (gx >= 12) return;
        int t = gx >> 2;
        src = (t < 2) ? Wq_enc + (size_t)t * 16384 : Wqf;
        dst = (t < 2) ? WQT + t * 16384 : WQFT;
        sstride = 128; dstride = 128; tr = (gx >> 1) & 1; tc = gx & 1;
    } else if (gy == 5) {    // WKV hi/lo: a = 2l + isV
        if (gx >= 16) return;
        int a = gx >> 2;
        src = ((a & 1) ? Wv_enc : Wk_enc) + (size_t)(a >> 1) * 16384;
        dst = WKVH + a * 16384; dstL = WKVL + a * 16384;
        sstride = 128; dstride = 128; tr = (gx >> 1) & 1; tc = gx & 1;
    } else {                 // Wvis: [2048][128] -> WVH/WVL [128][2048]
        src = Wvis; dst = WVH; dstL = WVL;
        sstride = 128; dstride = 2048; tr = gx >> 1; tc = gx & 1;
    }
    const int rb = tr * 64, cb = tc * 64;
    for (int o = tid; o < 64 * 64; o += 256) {
        int r = o >> 6, c = o & 63;
        tile[r][c] = src[(size_t)(rb + r) * sstride + cb + c];
    }
    __syncthreads();
    for (int o = tid; o < 64 * 64; o += 256) {
        int rn = o >> 6, ck = o & 63;
        float v = tile[ck][rn];
        short hi = bfc(v);
        size_t di = (size_t)(cb + rn) * dstride + rb + ck;
        dst[di] = hi;
        if (dstL) dstL[di] = bfc(v - b2f(hi));
    }
}

// -------- kernel P: visual=lf@Wvis, LN, K/V=visn@Wk/Wv — all MFMA, hi/lo -----
// 3-pass hi/lo (AhBh + AlBh + AhBl) keeps ~fp32 accuracy end to end.
// r10: 512 threads / 8 waves. r11: 3 independent accumulators (one per
// hi/lo pass) break the serial MFMA dependency chain (192 -> 3x64); final
// fp32 sum reassociates only (lo terms ~2^-8 of hi).
__global__ __launch_bounds__(512) void k_viskv(const float* __restrict__ lf,
                                               const short* __restrict__ WVH,
                                               const short* __restrict__ WVL,
                                               const short* __restrict__ WKVH,
                                               const short* __restrict__ WKVL,
                                               short* __restrict__ kvB) {
    __shared__ __align__(16) char smem[17408 + 4352];   // Ah|Al  /  vis | Vh | Vl
    __shared__ float sPa[256], sPb[256], sMean[16], sRstd[16];
    short* Ah = (short*)smem;                 // [16][136] bf16 (4352 B)
    short* Al = (short*)(smem + 4352);        // [16][136]
    float* vis = (float*)smem;                // [16][132] fp32 (8448 B, overlays Ah/Al)
    short* Vh = (short*)(smem + 8704);        // [16][136]
    short* Vl = (short*)(smem + 13056);       // [16][136]

    const int tid = threadIdx.x;              // 512 = 8 waves
    const int w = tid >> 6;                   // wave 0..7 -> out cols w*16..+15
    const int lane = tid & 63;
    const int lq = lane & 15;
    const int quad = lane >> 4;
    const int r0 = blockIdx.x * 16;           // 256 blocks x 16 rows

    // ---- phase 1: visual = lf @ Wvis  (K=2048 in 16 chunks of 128) ----
    f32x4 a0 = {0.f, 0.f, 0.f, 0.f};
    f32x4 a1 = {0.f, 0.f, 0.f, 0.f};
    f32x4 a2 = {0.f, 0.f, 0.f, 0.f};
    for (int c = 0; c < 16; ++c) {
        __syncthreads();                      // prior MFMA reads done before overwrite
        for (int o = tid; o < 16 * 128; o += 512) {
            int r = o >> 7, j = o & 127;
            float v = lf[(size_t)(r0 + r) * FD + c * 128 + j];
            short hi = bfc(v);
            Ah[r * 136 + j] = hi;
            Al[r * 136 + j] = bfc(v - b2f(hi));
        }
        __syncthreads();
#pragma unroll
        for (int ks = 0; ks < 4; ++ks) {
            bf16x8 ah = *(const bf16x8*)&Ah[lq * 136 + ks * 32 + quad * 8];
            bf16x8 al = *(const bf16x8*)&Al[lq * 136 + ks * 32 + quad * 8];
            const size_t bo = (size_t)(w * 16 + lq) * FD + c * 128 + ks * 32 + quad * 8;
            bf16x8 bh = *(const bf16x8*)&WVH[bo];
            bf16x8 bl = *(const bf16x8*)&WVL[bo];
            a0 = MFMA16(ah, bh, a0);
            a1 = MFMA16(al, bh, a1);
            a2 = MFMA16(ah, bl, a2);
        }
    }
    f32x4 acc = a0 + a1 + a2;
    __syncthreads();
    // C-layout -> vis[row][col] fp32 (row = quad*4+r, col = w*16+lq)
#pragma unroll
    for (int r = 0; r < 4; ++r)
        vis[(quad * 4 + r) * 132 + w * 16 + lq] = acc[r];
    __syncthreads();

    // ---- phase 2: LN over 128 cols per row (exact 256-thread tree kept;
    //      threads >=256 idle here) ----
    if (tid < 256) {
        int row = tid >> 4, p = tid & 15;     // 8 cols per thread
        float s = 0.f, s2 = 0.f;
#pragma unroll
        for (int k = 0; k < 8; ++k) { float v = vis[row * 132 + p * 8 + k]; s += v; s2 += v * v; }
        sPa[tid] = s; sPb[tid] = s2;
    }
    __syncthreads();
    if (tid < 16) {
        float s = 0.f, s2 = 0.f;
#pragma unroll
        for (int p = 0; p < 16; ++p) { s += sPa[tid * 16 + p]; s2 += sPb[tid * 16 + p]; }
        float m = s * (1.f / 128.f);
        float v = s2 * (1.f / 128.f) - m * m;
        sMean[tid] = m; sRstd[tid] = rsqrtf(v + 1e-5f);
    }
    __syncthreads();
    for (int o = tid; o < 16 * 128; o += 512) {
        int r = o >> 7, j = o & 127;
        float v = (vis[r * 132 + j] - sMean[r]) * sRstd[r];
        short hi = bfc(v);
        Vh[r * 136 + j] = hi;
        Vl[r * 136 + j] = bfc(v - b2f(hi));
    }
    __syncthreads();

    // ---- phase 3: K/V = visn @ Wk/Wv per array (K=128), bf16 out ----
    for (int a = 0; a < 4; ++a) {
        f32x4 k0 = {0.f, 0.f, 0.f, 0.f};
        f32x4 k1 = {0.f, 0.f, 0.f, 0.f};
        f32x4 k2 = {0.f, 0.f, 0.f, 0.f};
#pragma unroll
        for (int ks = 0; ks < 4; ++ks) {
            bf16x8 ah = *(const bf16x8*)&Vh[lq * 136 + ks * 32 + quad * 8];
            bf16x8 al = *(const bf16x8*)&Vl[lq * 136 + ks * 32 + quad * 8];
            const size_t bo = (size_t)a * 16384 + (size_t)(w * 16 + lq) * 128 + ks * 32 + quad * 8;
            bf16x8 bh = *(const bf16x8*)&WKVH[bo];
            bf16x8 bl = *(const bf16x8*)&WKVL[bo];
            k0 = MFMA16(ah, bh, k0);
            k1 = MFMA16(al, bh, k1);
            k2 = MFMA16(ah, bl, k2);
        }
        f32x4 ka = k0 + k1 + k2;
#pragma unroll
        for (int r = 0; r < 4; ++r)
            kvB[(size_t)a * ASTRIDE + (size_t)(PAD + r0 + quad * 4 + r) * DM + w * 16 + lq]
                = bfc(ka[r]);
    }
}

// -------- kernel 3: text = g @ W_txt ; Kf = text @ Wk_f ; Vf = text @ Wv_f ---
__global__ __launch_bounds__(128) void k_text(const float* __restrict__ g,
                                              const float* __restrict__ Wtxt,
                                              const float* __restrict__ Wkf,
                                              const float* __restrict__ Wvf,
                                              float* __restrict__ text,
                                              float* __restrict__ kf,
                                              float* __restrict__ vf) {
    __shared__ float gs[GFD];
    __shared__ float tr[DM];
    const int r = blockIdx.x;
    const int tid = threadIdx.x;
    for (int i = tid; i < GFD; i += 128) gs[i] = g[(size_t)r * GFD + i];
    __syncthreads();
    float acc = 0.f;
    for (int k = 0; k < GFD; ++k) acc += gs[k] * Wtxt[(size_t)k * DM + tid];
    tr[tid] = acc;
    text[(size_t)r * DM + tid] = acc;
    __syncthreads();
    float a1 = 0.f, a2 = 0.f;
    for (int k = 0; k < DM; ++k) {
        float x = tr[k];
        a1 += x * Wkf[(size_t)k * DM + tid];
        a2 += x * Wvf[(size_t)k * DM + tid];
    }
    kf[(size_t)r * DM + tid] = a1;
    vf[(size_t)r * DM + tid] = a2;
}

// ---------------- LN helpers for [64][STS] bf16 LDS tile ---------------------
__device__ __forceinline__ void ln_stats64(const short* buf, int tid, int dbl,
                                           float* pa, float* pb, float* ms, float* rs) {
    {
        int row = tid >> 3, p = tid & 7;
        const bf16x8* bp = (const bf16x8*)(buf + row * STS + p * 16);
        float s = 0.f, s2 = 0.f;
#pragma unroll
        for (int q8 = 0; q8 < 2; ++q8) {
            bf16x8 x = bp[q8];
#pragma unroll
            for (int e = 0; e < 8; ++e) { float v = b2f(x[e]); s += v; s2 += v * v; }
        }
        pa[tid] = s; pb[tid] = s2;
    }
    __syncthreads();
    if (tid < 64) {
        float ss = 0.f, ss2 = 0.f;
#pragma unroll
        for (int p2 = 0; p2 < 8; ++p2) { ss += pa[tid * 8 + p2]; ss2 += pb[tid * 8 + p2]; }
        float m = ss * (1.f / 128.f);
        float v = ss2 * (1.f / 128.f) - m * m;
        float r = rsqrtf(v + 1e-5f);
        if (dbl) r *= rsqrtf(v / (v + 1e-5f) + 1e-5f);   // exact LN(LN(x)) fold
        ms[tid] = m; rs[tid] = r;
    }
    __syncthreads();
}
__device__ __forceinline__ void ln_apply64(short* buf, int tid,
                                           const float* ms, const float* rs) {
    int row = tid >> 3, p = tid & 7;
    float m = ms[row], r = rs[row];
    bf16x8* bp = (bf16x8*)(buf + row * STS + p * 16);
#pragma unroll
    for (int q8 = 0; q8 < 2; ++q8) {
        bf16x8 x = bp[q8]; bf16x8 o;
#pragma unroll
        for (int e = 0; e < 8; ++e) o[e] = bfc((b2f(x[e]) - m) * r);
        bp[q8] = o;
    }
    __syncthreads();
}

// ---------------- kernel 4: 4 frames/block, MFMA attention + FFN -------------
__global__ __launch_bounds__(512, 4) void k_frames(
    const short* __restrict__ kvB,    const float* __restrict__ text,
    const float* __restrict__ kf,     const float* __restrict__ vf,
    const short* __restrict__ W1T,    const short* __restrict__ W2T,
    const short* __restrict__ WQT,    const short* __restrict__ WQFT,
    float* __restrict__ out) {
    __shared__ __align__(16) short sT[MROWS * STS];     // state (t / z / x / z2)
    __shared__ __align__(16) short sX[MROWS * STS];     // Q / H-chunk / Qf / z3
    __shared__ __align__(16) short sVT[128 * VTS];      // V^T union (dims x keys)
    __shared__ __align__(16) short sPB[8 * 16 * PBS];   // per-wave P; FFN H dbuf; kf/vf/scores
    __shared__ float sPa[512], sPb[512];
    __shared__ float sMean[64], sRstd[64];

    const int tid = threadIdx.x;        // 512 = 8 waves
    const int w = tid >> 6;             // wave 0..7
    const int lane = tid & 63;
    const int lq = lane & 15;
    const int quad = lane >> 4;
    // XCD-aware swizzle (T1): keeps each XCD on a contiguous frame chunk
    // (FETCH 115->99 MB verified r0->r6; time-neutral but strictly less HBM).
    const int bswz = (blockIdx.x & 7) * 128 + (blockIdx.x >> 3);
    const int T0 = bswz * FPB;

    // init: t rows m = f*16+q <- text[q][:]
    for (int o = tid; o < MROWS * 128; o += 512)
        sT[(o >> 7) * STS + (o & 127)] = bfc(text[((o >> 7) & 15) * 128 + (o & 127)]);
    __syncthreads();

    for (int l = 0; l < 2; ++l) {
        const short* kvK = kvB + (size_t)(2 * l) * ASTRIDE;
        const short* kvV = kvB + (size_t)(2 * l + 1) * ASTRIDE;

        // ---- stage V^T union (coalesced; barrier inside ln_stats covers it) --
        for (int o = tid; o < UROWS * 128; o += 512) {
            int u = o >> 7, d = o & 127;
            sVT[d * VTS + u] = kvV[(size_t)(T0 + u) * 128 + d];
        }
        ln_stats64(sT, tid, 0, sPa, sPb, sMean, sRstd);

        // ---- Q = LN(t) @ Wq[l] -> sX (LN applied inline on A-fragments) ----
        {
            const short* wq = WQT + (size_t)l * 16384;
            bf16x8 B[4];
#pragma unroll
            for (int ks = 0; ks < 4; ++ks)
                B[ks] = *(const bf16x8*)&wq[(w * 16 + lq) * 128 + ks * 32 + quad * 8];
#pragma unroll
            for (int mt = 0; mt < 4; ++mt) {
                int row = mt * 16 + lq;
                float m = sMean[row], r = sRstd[row];
                f32x4 acc = {0.f, 0.f, 0.f, 0.f};
#pragma unroll
                for (int ks = 0; ks < 4; ++ks) {
                    bf16x8 t8 = *(const bf16x8*)&sT[row * STS + ks * 32 + quad * 8];
                    bf16x8 a8;
#pragma unroll
                    for (int e = 0; e < 8; ++e) a8[e] = bfc((b2f(t8[e]) - m) * r);
                    acc = MFMA16(a8, B[ks], acc);
                }
#pragma unroll
                for (int r4 = 0; r4 < 4; ++r4)
                    sX[(mt * 16 + quad * 4 + r4) * STS + w * 16 + lq] = bfc(acc[r4]);
            }
        }
        __syncthreads();

        // ---- attention: wave pair (2f, 2f+1) handles frame f, 4 heads each --
        {
            const int f = w >> 1;
            const int hg = (w & 1) * 4;
            short* Pb = sPB + w * 16 * PBS;
            bf16x8 zv = {};
            for (int hh = 0; hh < 4; ++hh) {
                const int h = hg + hh;
                bf16x8 aq;
                {
                    bf16x8 t8 = *(const bf16x8*)&sX[(f * 16 + lq) * STS + h * 16 + (quad & 1) * 8];
                    aq = (quad < 2) ? t8 : zv;
                }
                f32x4 sc4[4];
#pragma unroll
                for (int kt = 0; kt < 4; ++kt) {
                    bf16x8 bk = *(const bf16x8*)&kvK[(size_t)(T0 + f + kt * 16 + lq) * 128 + h * 16 + (quad & 1) * 8];
                    bk = (quad < 2) ? bk : zv;
                    f32x4 z4 = {0.f, 0.f, 0.f, 0.f};
                    sc4[kt] = MFMA16(aq, bk, z4);
                }
                // softmax in C-layout registers; keep fp32 P values
                float pr[4][4];   // [r][kt]
#pragma unroll
                for (int r = 0; r < 4; ++r) {
                    float a0 = sc4[0][r] * 0.25f, a1 = sc4[1][r] * 0.25f;
                    float a2 = sc4[2][r] * 0.25f, a3 = sc4[3][r] * 0.25f;
                    float mx = fmaxf(fmaxf(a0, a1), fmaxf(a2, a3));
                    mx = fmaxf(mx, __shfl_xor(mx, 1));
                    mx = fmaxf(mx, __shfl_xor(mx, 2));
                    mx = fmaxf(mx, __shfl_xor(mx, 4));
                    mx = fmaxf(mx, __shfl_xor(mx, 8));
                    float e0 = expf(a0 - mx), e1 = expf(a1 - mx);
                    float e2 = expf(a2 - mx), e3 = expf(a3 - mx);
                    float s = e0 + e1 + e2 + e3;
                    s += __shfl_xor(s, 1);
                    s += __shfl_xor(s, 2);
                    s += __shfl_xor(s, 4);
                    s += __shfl_xor(s, 8);
                    float inv = 1.f / s;
                    pr[r][0] = e0 * inv; pr[r][1] = e1 * inv;
                    pr[r][2] = e2 * inv; pr[r][3] = e3 * inv;
                }
                // V^T window fragments once (register-resident across hi/lo passes)
                const short* vr = &sVT[(h * 16 + lq) * VTS];
                int4 v0 = *(const int4*)&vr[quad * 8];
                int4 v1 = *(const int4*)&vr[quad * 8 + 8];
                int4 u0 = *(const int4*)&vr[32 + quad * 8];
                int4 u1 = *(const int4*)&vr[32 + quad * 8 + 8];
                bf16x8 b0 = shiftf(v0, v1, f);
                bf16x8 b1 = shiftf(u0, u1, f);
                // PV with hi+lo bf16 split of P (extra precision margin).
                f32x4 ctx = {0.f, 0.f, 0.f, 0.f};
#pragma unroll
                for (int pass = 0; pass < 2; ++pass) {
#pragma unroll
                    for (int r = 0; r < 4; ++r)
#pragma unroll
                        for (int kt = 0; kt < 4; ++kt) {
                            float p = pr[r][kt];
                            short hi = bfc(p);
                            short v16 = pass == 0 ? hi : bfc(p - b2f(hi));
                            Pb[(quad * 4 + r) * PBS + kt * 16 + lq] = v16;
                        }
                    bf16x8 p0 = *(const bf16x8*)&Pb[lq * PBS + quad * 8];
                    bf16x8 p1 = *(const bf16x8*)&Pb[lq * PBS + 32 + quad * 8];
                    ctx = MFMA16(p0, b0, ctx);
                    ctx = MFMA16(p1, b1, ctx);
                }
                // z = ctx + tq  (tq recomputed from t + stats, fp32)
#pragma unroll
                for (int r = 0; r < 4; ++r) {
                    int row = f * 16 + quad * 4 + r;
                    int col = h * 16 + lq;
                    float tq = (b2f(sT[row * STS + col]) - sMean[row]) * sRstd[row];
                    sT[row * STS + col] = bfc(ctx[r] + tq);
                }
            }
        }
        __syncthreads();

        // ---- x = LN(LN(z)) in place ----
        ln_stats64(sT, tid, 1, sPa, sPb, sMean, sRstd);
        ln_apply64(sT, tid, sMean, sRstd);

        // ---- FFN: z2 = relu(x@W1)@W2 + x -> sT ----
        // H dbuf through sX/sPB (r9). r11: GEMM1 operands swapped
        // (MFMA16(B1,XA) -> D rows = H-cols, cols = x-rows) so each lane's 4
        // regs land on 4 CONTIGUOUS H cols -> one b64 store instead of 16
        // scalar b16 stores per mt. Same products/accumulation order ->
        // bit-identical H. GEMM2 reads the identical H matrix, unchanged.
        {
            const short* w1p = W1T + (size_t)l * 262144;
            const short* w2p = W2T + (size_t)l * 262144;
            bf16x8 XA[4][4];
#pragma unroll
            for (int mt = 0; mt < 4; ++mt)
#pragma unroll
                for (int ks = 0; ks < 4; ++ks)
                    XA[mt][ks] = *(const bf16x8*)&sT[(mt * 16 + lq) * STS + ks * 32 + quad * 8];
            f32x4 yacc[4];
#pragma unroll
            for (int mt = 0; mt < 4; ++mt) yacc[mt] = (f32x4){0.f, 0.f, 0.f, 0.f};
            // prologue: GEMM1 chunk 0 -> sX (buffer 0)
            {
                f32x4 hacc[4];
#pragma unroll
                for (int mt = 0; mt < 4; ++mt) hacc[mt] = (f32x4){0.f, 0.f, 0.f, 0.f};
#pragma unroll
                for (int ks = 0; ks < 4; ++ks) {
                    bf16x8 B1 = *(const bf16x8*)&w1p[(size_t)(w * 16 + lq) * 128 + ks * 32 + quad * 8];
#pragma unroll
                    for (int mt = 0; mt < 4; ++mt) hacc[mt] = MFMA16(B1, XA[mt][ks], hacc[mt]);
                }
#pragma unroll
                for (int mt = 0; mt < 4; ++mt) {
                    s16x4 hv;
#pragma unroll
                    for (int r = 0; r < 4; ++r) hv[r] = bfc(fmaxf(hacc[mt][r], 0.f));
                    *(s16x4*)&sX[(mt * 16 + lq) * STS + w * 16 + quad * 4] = hv;
                }
            }
            __syncthreads();
            for (int c = 0; c < 16; ++c) {
                short* Hr = (c & 1) ? sPB : sX;          // chunk c lives here
                if (c < 15) {
                    short* Hw = (c & 1) ? sX : sPB;      // chunk c+1 target
                    f32x4 hacc[4];
#pragma unroll
                    for (int mt = 0; mt < 4; ++mt) hacc[mt] = (f32x4){0.f, 0.f, 0.f, 0.f};
#pragma unroll
                    for (int ks = 0; ks < 4; ++ks) {
                        bf16x8 B1 = *(const bf16x8*)&w1p[(size_t)((c + 1) * 128 + w * 16 + lq) * 128 + ks * 32 + quad * 8];
#pragma unroll
                        for (int mt = 0; mt < 4; ++mt) hacc[mt] = MFMA16(B1, XA[mt][ks], hacc[mt]);
                    }
#pragma unroll
                    for (int mt = 0; mt < 4; ++mt) {
                        s16x4 hv;
#pragma unroll
                        for (int r = 0; r < 4; ++r) hv[r] = bfc(fmaxf(hacc[mt][r], 0.f));
                        *(s16x4*)&Hw[(mt * 16 + lq) * STS + w * 16 + quad * 4] = hv;
                    }
                }
                // GEMM2(c): wave w -> out cols w*16..+15, accumulate
#pragma unroll
                for (int ks = 0; ks < 4; ++ks) {
                    bf16x8 B2 = *(const bf16x8*)&w2p[(size_t)(w * 16 + lq) * 2048 + c * 128 + ks * 32 + quad * 8];
#pragma unroll
                    for (int mt = 0; mt < 4; ++mt) {
                        bf16x8 A = *(const bf16x8*)&Hr[(mt * 16 + lq) * STS + ks * 32 + quad * 8];
                        yacc[mt] = MFMA16(A, B2, yacc[mt]);
                    }
                }
                __syncthreads();
            }
            // z2 = Y + x
#pragma unroll
            for (int mt = 0; mt < 4; ++mt)
#pragma unroll
                for (int r = 0; r < 4; ++r) {
                    int row = mt * 16 + quad * 4 + r;
                    int col = w * 16 + lq;
                    sT[row * STS + col] = bfc(yacc[mt][r] + b2f(sT[row * STS + col]));
                }
        }
        __syncthreads();

        // ---- t = LN(z2) in place ----
        ln_stats64(sT, tid, 0, sPa, sPb, sMean, sRstd);
        ln_apply64(sT, tid, sMean, sRstd);
    }

    // ================= final single-head attention (d_q = 128) ==============
    // Qf = t @ Wq_f -> sX
    {
        bf16x8 B[4];
#pragma unroll
        for (int ks = 0; ks < 4; ++ks)
            B[ks] = *(const bf16x8*)&WQFT[(w * 16 + lq) * 128 + ks * 32 + quad * 8];
#pragma unroll
        for (int mt = 0; mt < 4; ++mt) {
            f32x4 acc = {0.f, 0.f, 0.f, 0.f};
#pragma unroll
            for (int ks = 0; ks < 4; ++ks) {
                bf16x8 A = *(const bf16x8*)&sT[(mt * 16 + lq) * STS + ks * 32 + quad * 8];
                acc = MFMA16(A, B[ks], acc);
            }
#pragma unroll
            for (int r = 0; r < 4; ++r)
                sX[(mt * 16 + quad * 4 + r) * STS + w * 16 + lq] = bfc(acc[r]);
        }
    }
    // stage kf/vf + score buffer in sPB (dead)
    short* kfL = sPB;
    short* vfL = sPB + 16 * STS;
    float* scF = (float*)(sPB + 2 * 16 * STS);       // [64][17] fp32
    for (int o = tid; o < 2048; o += 512) {
        kfL[(o >> 7) * STS + (o & 127)] = bfc(kf[o]);
        vfL[(o >> 7) * STS + (o & 127)] = bfc(vf[o]);
    }
    __syncthreads();
    // scores[m][k] = Qf[m] . kf[k] / sqrt(128)
    if (tid < 256) {
        int m = tid >> 2, kq = tid & 3;
        float a4[4] = {0.f, 0.f, 0.f, 0.f};
        for (int d8 = 0; d8 < 16; ++d8) {
            bf16x8 qc = *(const bf16x8*)&sX[m * STS + d8 * 8];
            float qf[8];
#pragma unroll
            for (int e = 0; e < 8; ++e) qf[e] = b2f(qc[e]);
#pragma unroll
            for (int k = 0; k < 4; ++k) {
                bf16x8 kc = *(const bf16x8*)&kfL[(kq * 4 + k) * STS + d8 * 8];
#pragma unroll
                for (int e = 0; e < 8; ++e) a4[k] += qf[e] * b2f(kc[e]);
            }
        }
#pragma unroll
        for (int k = 0; k < 4; ++k)
            scF[m * 17 + kq * 4 + k] = a4[k] * 0.08838834764831845f;
    }
    __syncthreads();
    if (tid < 64) {
        float* row = scF + tid * 17;
        float mx = row[0];
#pragma unroll
        for (int k = 1; k < 16; ++k) mx = fmaxf(mx, row[k]);
        float sum = 0.f;
#pragma unroll
        for (int k = 0; k < 16; ++k) { float e = expf(row[k] - mx); row[k] = e; sum += e; }
        float inv = 1.f / sum;
#pragma unroll
        for (int k = 0; k < 16; ++k) row[k] *= inv;
    }
    __syncthreads();
    // z3 = attn @ vf + t -> sX
    {
        int jj = tid & 127, rr0 = tid >> 7;
        float vv[16];
#pragma unroll
        for (int k = 0; k < 16; ++k) vv[k] = b2f(vfL[k * STS + jj]);
#pragma unroll 4
        for (int rr = 0; rr < 16; ++rr) {
            int row = rr0 + 4 * rr;
            float acc = 0.f;
#pragma unroll
            for (int k = 0; k < 16; ++k) acc += scF[row * 17 + k] * vv[k];
            sX[row * STS + jj] = bfc(acc + b2f(sT[row * STS + jj]));
        }
    }
    __syncthreads();
    // out = LN(z3), fp32
    ln_stats64(sX, tid, 0, sPa, sPb, sMean, sRstd);
    for (int o = tid; o < MROWS * 128; o += 512) {
        int r = o >> 7;
        out[(size_t)T0 * 2048 + o] = (b2f(sX[r * STS + (o & 127)]) - sMean[r]) * sRstd[r];
    }
}

extern "C" void kernel_launch(void* const* d_in, const int* in_sizes, int n_in,
                              void* d_out, int out_size, void* d_ws, size_t ws_size,
                              hipStream_t stream) {
    const float* g      = (const float*)d_in[0];
    const float* lf     = (const float*)d_in[1];
    const float* Wvis   = (const float*)d_in[2];
    const float* Wtxt   = (const float*)d_in[3];
    const float* Wq_enc = (const float*)d_in[4];
    const float* Wk_enc = (const float*)d_in[5];
    const float* Wv_enc = (const float*)d_in[6];
    const float* W1f    = (const float*)d_in[7];
    const float* W2f    = (const float*)d_in[8];
    const float* Wqf    = (const float*)d_in[9];
    const float* Wkf    = (const float*)d_in[10];
    const float* Wvf    = (const float*)d_in[11];
    float* out = (float*)d_out;
    float* ws  = (float*)d_ws;

    short* WVH  = (short*)(ws + OFF_WVH);
    short* WVL  = (short*)(ws + OFF_WVL);
    short* WKVH = (short*)(ws + OFF_WKVH);
    short* WKVL = (short*)(ws + OFF_WKVL);
    short* kvB  = (short*)(ws + OFF_KV);
    float* text = ws + OFF_TEXT;
    float* kfp  = ws + OFF_KF;
    float* vfp  = ws + OFF_VF;
    short* W1T  = (short*)(ws + OFF_W1T);
    short* W2T  = (short*)(ws + OFF_W2T);
    short* WQT  = (short*)(ws + OFF_WQT);
    short* WQFT = (short*)(ws + OFF_WQFT);

    // zero only the 63 pad rows at the head of each bf16 K/V array
    for (int a = 0; a < 4; ++a)
        hipMemsetAsync(kvB + (size_t)a * ASTRIDE, 0, (size_t)PAD * DM * sizeof(short), stream);

    k_wcvt <<<dim3(64, 7), dim3(256), 0, stream>>>(Wq_enc, W1f, W2f, Wqf, Wk_enc, Wv_enc, Wvis,
                                                   W1T, W2T, WQT, WQFT, WKVH, WKVL, WVH, WVL);
    k_viskv<<<dim3(TFRAMES / 16), dim3(512), 0, stream>>>(lf, WVH, WVL, WKVH, WKVL, kvB);
    k_text <<<dim3(NG), dim3(128), 0, stream>>>(g, Wtxt, Wkf, Wvf, text, kfp, vfp);
    k_frames<<<dim3(TFRAMES / FPB), dim3(512), 0, stream>>>(kvB, text, kfp, vfp, W1T, W2T, WQT, WQFT, out);
}

// Round 12
// 548.061 us; speedup vs baseline: 1.1012x; 1.0412x over previous
//
#include <hip/hip_runtime.h>
#include <math.h>

#define TFRAMES 4096
#define DM 128
#define LQ 64
#define NG 16
#define NH 8
#define DQH 16
#define FD 2048
#define GFD 512
#define PAD 63
#define KVROWS (TFRAMES + PAD)      /* 4159 */
#define ASTRIDE (KVROWS * DM)       /* 532352 SHORTS per bf16 K/V array */
#define FPB 4                       /* frames per block */
#define MROWS (FPB * NG)            /* 64 state rows per block */
#define STS 136                     /* state row stride (shorts, mult of 8) */
#define VTS 72                      /* V^T row stride (shorts) */
#define PBS 72                      /* P buffer row stride (shorts) */
#define UROWS (LQ + FPB - 1)        /* 67 K/V union rows */

/* ws layout (floats). */
#define OFF_WVH  0                                 /* Wvis^T hi: 128x2048 sh = 131072 fl */
#define OFF_WVL  131072
#define OFF_WKVH 262144                            /* Wk/Wv^T hi: 4x16384 sh = 32768 fl */
#define OFF_WKVL 294912
#define OFF_KV   (TFRAMES * DM)                    /* 524288 */
#define OFF_TEXT (OFF_KV + 2 * ASTRIDE)
#define OFF_KF   (OFF_TEXT + NG * DM)
#define OFF_VF   (OFF_KF + NG * DM)
#define OFF_W1T  (OFF_VF + NG * DM)
#define OFF_W2T  (OFF_W1T + 262144)
#define OFF_WQT  (OFF_W2T + 262144)
#define OFF_WQFT (OFF_WQT + 16384)

typedef __attribute__((ext_vector_type(8))) short bf16x8;
typedef __attribute__((ext_vector_type(4))) short s16x4;
typedef __attribute__((ext_vector_type(4))) float f32x4;
#define MFMA16(a, b, c) __builtin_amdgcn_mfma_f32_16x16x32_bf16(a, b, c, 0, 0, 0)

// f32->bf16 RNE via the compiler's native __bf16 cast (r8-verified: PASS,
// VALUBusy 38->33%, dur 442->432; bit-identical absmax).
__device__ __forceinline__ short bfc(float x) {
    union { __bf16 b; short s; } v;
    v.b = (__bf16)x;
    return v.s;
}
__device__ __forceinline__ float b2f(short s) {
    union { unsigned u; float f; } v;
    v.u = ((unsigned)(unsigned short)s) << 16;
    return v.f;
}
// Extract 8 shorts starting at short-offset f (0..3) from the 12-short window
// {a.x..a.w, b.x, b.y}. v_alignbit_b32 shift is 5-bit (wraps at 32!), so split
// f into a word offset (wo = f>>1, uniform select) + residual 0/16-bit shift.
__device__ __forceinline__ bf16x8 shiftf(int4 a, int4 b, int f) {
    const int wo = f >> 1;
    const int sh = (f & 1) * 16;
    int w0 = wo ? a.y : a.x;
    int w1 = wo ? a.z : a.y;
    int w2 = wo ? a.w : a.z;
    int w3 = wo ? b.x : a.w;
    int w4 = wo ? b.y : b.x;
    int o0 = __builtin_amdgcn_alignbit(w1, w0, sh);
    int o1 = __builtin_amdgcn_alignbit(w2, w1, sh);
    int o2 = __builtin_amdgcn_alignbit(w3, w2, sh);
    int o3 = __builtin_amdgcn_alignbit(w4, w3, sh);
    int4 o = {o0, o1, o2, o3};
    return *(bf16x8*)&o;
}

// -------- kernel W: unified coalesced LDS tile-transpose of all weights ------
__global__ __launch_bounds__(256) void k_wcvt(const float* __restrict__ Wq_enc,
                                              const float* __restrict__ W1f,
                                              const float* __restrict__ W2f,
                                              const float* __restrict__ Wqf,
                                              const float* __restrict__ Wk_enc,
                                              const float* __restrict__ Wv_enc,
                                              const float* __restrict__ Wvis,
                                              short* __restrict__ W1T,
                                              short* __restrict__ W2T,
                                              short* __restrict__ WQT,
                                              short* __restrict__ WQFT,
                                              short* __restrict__ WKVH,
                                              short* __restrict__ WKVL,
                                              short* __restrict__ WVH,
                                              short* __restrict__ WVL) {
    __shared__ float tile[64][65];
    const int tid = threadIdx.x;
    const int gy = blockIdx.y, gx = blockIdx.x;
    const float* src; short* dst; short* dstL = nullptr;
    int sstride, dstride, tr, tc;
    if (gy < 2) {            // W1: [128][2048] -> W1T [2048][128]
        src = W1f + (size_t)gy * 262144; dst = W1T + gy * 262144;
        sstride = 2048; dstride = 128; tr = gx >> 5; tc = gx & 31;
    } else if (gy < 4) {     // W2: [2048][128] -> W2T [128][2048]
        int l = gy - 2;
        src = W2f + (size_t)l * 262144; dst = W2T + l * 262144;
        sstride = 128; dstride = 2048; tr = gx >> 1; tc = gx & 1;
    } else if (gy == 4) {    // WQ l0,l1, WQF: [128][128]
        if (gx >= 12) return;
        int t = gx >> 2;
        src = (t < 2) ? Wq_enc + (size_t)t * 16384 : Wqf;
        dst = (t < 2) ? WQT + t * 16384 : WQFT;
        sstride = 128; dstride = 128; tr = (gx >> 1) & 1; tc = gx & 1;
    } else if (gy == 5) {    // WKV hi/lo: a = 2l + isV
        if (gx >= 16) return;
        int a = gx >> 2;
        src = ((a & 1) ? Wv_enc : Wk_enc) + (size_t)(a >> 1) * 16384;
        dst = WKVH + a * 16384; dstL = WKVL + a * 16384;
        sstride = 128; dstride = 128; tr = (gx >> 1) & 1; tc = gx & 1;
    } else {                 // Wvis: [2048][128] -> WVH/WVL [128][2048]
        src = Wvis; dst = WVH; dstL = WVL;
        sstride = 128; dstride = 2048; tr = gx >> 1; tc = gx & 1;
    }
    const int rb = tr * 64, cb = tc * 64;
    for (int o = tid; o < 64 * 64; o += 256) {
        int r = o >> 6, c = o & 63;
        tile[r][c] = src[(size_t)(rb + r) * sstride + cb + c];
    }
    __syncthreads();
    for (int o = tid; o < 64 * 64; o += 256) {
        int rn = o >> 6, ck = o & 63;
        float v = tile[ck][rn];
        short hi = bfc(v);
        size_t di = (size_t)(cb + rn) * dstride + rb + ck;
        dst[di] = hi;
        if (dstL) dstL[di] = bfc(v - b2f(hi));
    }
}

// -------- kernel P: visual=lf@Wvis, LN, K/V=visn@Wk/Wv — all MFMA, hi/lo -----
// 3-pass hi/lo (AhBh + AlBh + AhBl) keeps ~fp32 accuracy end to end.
// r10: 512 threads / 8 waves. r11: 3 independent accumulators (neutral, kept).
// r12: float4 staging (was scalar) + register prefetch of chunk c+1 during
// chunk-c MFMAs — the kernel is latency-bound (1 block/CU, 16 serial chunks).
__global__ __launch_bounds__(512) void k_viskv(const float* __restrict__ lf,
                                               const short* __restrict__ WVH,
                                               const short* __restrict__ WVL,
                                               const short* __restrict__ WKVH,
                                               const short* __restrict__ WKVL,
                                               short* __restrict__ kvB) {
    __shared__ __align__(16) char smem[17408 + 4352];   // Ah|Al  /  vis | Vh | Vl
    __shared__ float sPa[256], sPb[256], sMean[16], sRstd[16];
    short* Ah = (short*)smem;                 // [16][136] bf16 (4352 B)
    short* Al = (short*)(smem + 4352);        // [16][136]
    float* vis = (float*)smem;                // [16][132] fp32 (8448 B, overlays Ah/Al)
    short* Vh = (short*)(smem + 8704);        // [16][136]
    short* Vl = (short*)(smem + 13056);       // [16][136]

    const int tid = threadIdx.x;              // 512 = 8 waves
    const int w = tid >> 6;                   // wave 0..7 -> out cols w*16..+15
    const int lane = tid & 63;
    const int lq = lane & 15;
    const int quad = lane >> 4;
    const int r0 = blockIdx.x * 16;           // 256 blocks x 16 rows

    // ---- phase 1: visual = lf @ Wvis  (K=2048 in 16 chunks of 128) ----
    const int sr = tid >> 5;                  // staging row 0..15
    const int sj = tid & 31;                  // float4 group 0..31
    const float* lfp = lf + (size_t)(r0 + sr) * FD + sj * 4;
    float4 pf = *(const float4*)lfp;          // prefetch chunk 0
    f32x4 a0 = {0.f, 0.f, 0.f, 0.f};
    f32x4 a1 = {0.f, 0.f, 0.f, 0.f};
    f32x4 a2 = {0.f, 0.f, 0.f, 0.f};
    for (int c = 0; c < 16; ++c) {
        __syncthreads();                      // prior MFMA reads done before overwrite
        {
            float4 v = pf;
            short h0 = bfc(v.x), h1 = bfc(v.y), h2 = bfc(v.z), h3 = bfc(v.w);
            s16x4 hv = {h0, h1, h2, h3};
            s16x4 lv = {bfc(v.x - b2f(h0)), bfc(v.y - b2f(h1)),
                        bfc(v.z - b2f(h2)), bfc(v.w - b2f(h3))};
            *(s16x4*)&Ah[sr * 136 + sj * 4] = hv;
            *(s16x4*)&Al[sr * 136 + sj * 4] = lv;
        }
        if (c < 15) pf = *(const float4*)(lfp + (c + 1) * 128);  // hide HBM latency
        __syncthreads();
#pragma unroll
        for (int ks = 0; ks < 4; ++ks) {
            bf16x8 ah = *(const bf16x8*)&Ah[lq * 136 + ks * 32 + quad * 8];
            bf16x8 al = *(const bf16x8*)&Al[lq * 136 + ks * 32 + quad * 8];
            const size_t bo = (size_t)(w * 16 + lq) * FD + c * 128 + ks * 32 + quad * 8;
            bf16x8 bh = *(const bf16x8*)&WVH[bo];
            bf16x8 bl = *(const bf16x8*)&WVL[bo];
            a0 = MFMA16(ah, bh, a0);
            a1 = MFMA16(al, bh, a1);
            a2 = MFMA16(ah, bl, a2);
        }
    }
    f32x4 acc = a0 + a1 + a2;
    __syncthreads();
    // C-layout -> vis[row][col] fp32 (row = quad*4+r, col = w*16+lq)
#pragma unroll
    for (int r = 0; r < 4; ++r)
        vis[(quad * 4 + r) * 132 + w * 16 + lq] = acc[r];
    __syncthreads();

    // ---- phase 2: LN over 128 cols per row (exact 256-thread tree kept;
    //      threads >=256 idle here) ----
    if (tid < 256) {
        int row = tid >> 4, p = tid & 15;     // 8 cols per thread
        float s = 0.f, s2 = 0.f;
#pragma unroll
        for (int k = 0; k < 8; ++k) { float v = vis[row * 132 + p * 8 + k]; s += v; s2 += v * v; }
        sPa[tid] = s; sPb[tid] = s2;
    }
    __syncthreads();
    if (tid < 16) {
        float s = 0.f, s2 = 0.f;
#pragma unroll
        for (int p = 0; p < 16; ++p) { s += sPa[tid * 16 + p]; s2 += sPb[tid * 16 + p]; }
        float m = s * (1.f / 128.f);
        float v = s2 * (1.f / 128.f) - m * m;
        sMean[tid] = m; sRstd[tid] = rsqrtf(v + 1e-5f);
    }
    __syncthreads();
    for (int o = tid; o < 16 * 128; o += 512) {
        int r = o >> 7, j = o & 127;
        float v = (vis[r * 132 + j] - sMean[r]) * sRstd[r];
        short hi = bfc(v);
        Vh[r * 136 + j] = hi;
        Vl[r * 136 + j] = bfc(v - b2f(hi));
    }
    __syncthreads();

    // ---- phase 3: K/V = visn @ Wk/Wv per array (K=128), bf16 out ----
    for (int a = 0; a < 4; ++a) {
        f32x4 k0 = {0.f, 0.f, 0.f, 0.f};
        f32x4 k1 = {0.f, 0.f, 0.f, 0.f};
        f32x4 k2 = {0.f, 0.f, 0.f, 0.f};
#pragma unroll
        for (int ks = 0; ks < 4; ++ks) {
            bf16x8 ah = *(const bf16x8*)&Vh[lq * 136 + ks * 32 + quad * 8];
            bf16x8 al = *(const bf16x8*)&Vl[lq * 136 + ks * 32 + quad * 8];
            const size_t bo = (size_t)a * 16384 + (size_t)(w * 16 + lq) * 128 + ks * 32 + quad * 8;
            bf16x8 bh = *(const bf16x8*)&WKVH[bo];
            bf16x8 bl = *(const bf16x8*)&WKVL[bo];
            k0 = MFMA16(ah, bh, k0);
            k1 = MFMA16(al, bh, k1);
            k2 = MFMA16(ah, bl, k2);
        }
        f32x4 ka = k0 + k1 + k2;
#pragma unroll
        for (int r = 0; r < 4; ++r)
            kvB[(size_t)a * ASTRIDE + (size_t)(PAD + r0 + quad * 4 + r) * DM + w * 16 + lq]
                = bfc(ka[r]);
    }
}

// -------- kernel 3: text = g @ W_txt ; Kf = text @ Wk_f ; Vf = text @ Wv_f ---
__global__ __launch_bounds__(128) void k_text(const float* __restrict__ g,
                                              const float* __restrict__ Wtxt,
                                              const float* __restrict__ Wkf,
                                              const float* __restrict__ Wvf,
                                              float* __restrict__ text,
                                              float* __restrict__ kf,
                                              float* __restrict__ vf) {
    __shared__ float gs[GFD];
    __shared__ float tr[DM];
    const int r = blockIdx.x;
    const int tid = threadIdx.x;
    for (int i = tid; i < GFD; i += 128) gs[i] = g[(size_t)r * GFD + i];
    __syncthreads();
    float acc = 0.f;
    for (int k = 0; k < GFD; ++k) acc += gs[k] * Wtxt[(size_t)k * DM + tid];
    tr[tid] = acc;
    text[(size_t)r * DM + tid] = acc;
    __syncthreads();
    float a1 = 0.f, a2 = 0.f;
    for (int k = 0; k < DM; ++k) {
        float x = tr[k];
        a1 += x * Wkf[(size_t)k * DM + tid];
        a2 += x * Wvf[(size_t)k * DM + tid];
    }
    kf[(size_t)r * DM + tid] = a1;
    vf[(size_t)r * DM + tid] = a2;
}

// ---------------- LN helpers for [64][STS] bf16 LDS tile ---------------------
__device__ __forceinline__ void ln_stats64(const short* buf, int tid, int dbl,
                                           float* pa, float* pb, float* ms, float* rs) {
    {
        int row = tid >> 3, p = tid & 7;
        const bf16x8* bp = (const bf16x8*)(buf + row * STS + p * 16);
        float s = 0.f, s2 = 0.f;
#pragma unroll
        for (int q8 = 0; q8 < 2; ++q8) {
            bf16x8 x = bp[q8];
#pragma unroll
            for (int e = 0; e < 8; ++e) { float v = b2f(x[e]); s += v; s2 += v * v; }
        }
        pa[tid] = s; pb[tid] = s2;
    }
    __syncthreads();
    if (tid < 64) {
        float ss = 0.f, ss2 = 0.f;
#pragma unroll
        for (int p2 = 0; p2 < 8; ++p2) { ss += pa[tid * 8 + p2]; ss2 += pb[tid * 8 + p2]; }
        float m = ss * (1.f / 128.f);
        float v = ss2 * (1.f / 128.f) - m * m;
        float r = rsqrtf(v + 1e-5f);
        if (dbl) r *= rsqrtf(v / (v + 1e-5f) + 1e-5f);   // exact LN(LN(x)) fold
        ms[tid] = m; rs[tid] = r;
    }
    __syncthreads();
}
__device__ __forceinline__ void ln_apply64(short* buf, int tid,
                                           const float* ms, const float* rs) {
    int row = tid >> 3, p = tid & 7;
    float m = ms[row], r = rs[row];
    bf16x8* bp = (bf16x8*)(buf + row * STS + p * 16);
#pragma unroll
    for (int q8 = 0; q8 < 2; ++q8) {
        bf16x8 x = bp[q8]; bf16x8 o;
#pragma unroll
        for (int e = 0; e < 8; ++e) o[e] = bfc((b2f(x[e]) - m) * r);
        bp[q8] = o;
    }
    __syncthreads();
}

// ---------------- kernel 4: 4 frames/block, MFMA attention + FFN -------------
__global__ __launch_bounds__(512, 4) void k_frames(
    const short* __restrict__ kvB,    const float* __restrict__ text,
    const float* __restrict__ kf,     const float* __restrict__ vf,
    const short* __restrict__ W1T,    const short* __restrict__ W2T,
    const short* __restrict__ WQT,    const short* __restrict__ WQFT,
    float* __restrict__ out) {
    __shared__ __align__(16) short sT[MROWS * STS];     // state (t / z / x / z2)
    __shared__ __align__(16) short sX[MROWS * STS];     // Q / H-chunk / Qf / z3
    __shared__ __align__(16) short sVT[128 * VTS];      // V^T union (dims x keys)
    __shared__ __align__(16) short sPB[8 * 16 * PBS];   // LN(t) copy; per-wave P; FFN H dbuf; kf/vf/scores
    __shared__ float sPa[512], sPb[512];
    __shared__ float sMean[64], sRstd[64];

    const int tid = threadIdx.x;        // 512 = 8 waves
    const int w = tid >> 6;             // wave 0..7
    const int lane = tid & 63;
    const int lq = lane & 15;
    const int quad = lane >> 4;
    // XCD-aware swizzle (T1): keeps each XCD on a contiguous frame chunk
    // (FETCH 115->99 MB verified r0->r6; time-neutral but strictly less HBM).
    const int bswz = (blockIdx.x & 7) * 128 + (blockIdx.x >> 3);
    const int T0 = bswz * FPB;

    // init: t rows m = f*16+q <- text[q][:]
    for (int o = tid; o < MROWS * 128; o += 512)
        sT[(o >> 7) * STS + (o & 127)] = bfc(text[((o >> 7) & 15) * 128 + (o & 127)]);
    __syncthreads();

    for (int l = 0; l < 2; ++l) {
        const short* kvK = kvB + (size_t)(2 * l) * ASTRIDE;
        const short* kvV = kvB + (size_t)(2 * l + 1) * ASTRIDE;

        // ---- stage V^T union (coalesced; barrier inside ln_stats covers it) --
        for (int o = tid; o < UROWS * 128; o += 512) {
            int u = o >> 7, d = o & 127;
            sVT[d * VTS + u] = kvV[(size_t)(T0 + u) * 128 + d];
        }
        ln_stats64(sT, tid, 0, sPa, sPb, sMean, sRstd);

        // ---- normalize t ONCE -> sPB (r12: was recomputed inline by all 8
        //      waves on their A-fragments = 8x redundant bfc+fma; same
        //      formula & rounding -> bit-identical Q) ----
        {
            int row = tid >> 3, p = tid & 7;
            float m = sMean[row], r = sRstd[row];
            const bf16x8* tp = (const bf16x8*)(sT + row * STS + p * 16);
            bf16x8* np = (bf16x8*)(sPB + row * STS + p * 16);
#pragma unroll
            for (int q8 = 0; q8 < 2; ++q8) {
                bf16x8 x = tp[q8]; bf16x8 o;
#pragma unroll
                for (int e = 0; e < 8; ++e) o[e] = bfc((b2f(x[e]) - m) * r);
                np[q8] = o;
            }
        }
        __syncthreads();

        // ---- Q = LN(t) @ Wq[l] -> sX (plain MFMA reads of the shared copy) --
        {
            const short* wq = WQT + (size_t)l * 16384;
            bf16x8 B[4];
#pragma unroll
            for (int ks = 0; ks < 4; ++ks)
                B[ks] = *(const bf16x8*)&wq[(w * 16 + lq) * 128 + ks * 32 + quad * 8];
#pragma unroll
            for (int mt = 0; mt < 4; ++mt) {
                f32x4 acc = {0.f, 0.f, 0.f, 0.f};
#pragma unroll
                for (int ks = 0; ks < 4; ++ks) {
                    bf16x8 a8 = *(const bf16x8*)&sPB[(mt * 16 + lq) * STS + ks * 32 + quad * 8];
                    acc = MFMA16(a8, B[ks], acc);
                }
#pragma unroll
                for (int r4 = 0; r4 < 4; ++r4)
                    sX[(mt * 16 + quad * 4 + r4) * STS + w * 16 + lq] = bfc(acc[r4]);
            }
        }
        __syncthreads();

        // ---- attention: wave pair (2f, 2f+1) handles frame f, 4 heads each --
        {
            const int f = w >> 1;
            const int hg = (w & 1) * 4;
            short* Pb = sPB + w * 16 * PBS;
            bf16x8 zv = {};
            for (int hh = 0; hh < 4; ++hh) {
                const int h = hg + hh;
                bf16x8 aq;
                {
                    bf16x8 t8 = *(const bf16x8*)&sX[(f * 16 + lq) * STS + h * 16 + (quad & 1) * 8];
                    aq = (quad < 2) ? t8 : zv;
                }
                f32x4 sc4[4];
#pragma unroll
                for (int kt = 0; kt < 4; ++kt) {
                    bf16x8 bk = *(const bf16x8*)&kvK[(size_t)(T0 + f + kt * 16 + lq) * 128 + h * 16 + (quad & 1) * 8];
                    bk = (quad < 2) ? bk : zv;
                    f32x4 z4 = {0.f, 0.f, 0.f, 0.f};
                    sc4[kt] = MFMA16(aq, bk, z4);
                }
                // softmax in C-layout registers; keep fp32 P values
                float pr[4][4];   // [r][kt]
#pragma unroll
                for (int r = 0; r < 4; ++r) {
                    float a0 = sc4[0][r] * 0.25f, a1 = sc4[1][r] * 0.25f;
                    float a2 = sc4[2][r] * 0.25f, a3 = sc4[3][r] * 0.25f;
                    float mx = fmaxf(fmaxf(a0, a1), fmaxf(a2, a3));
                    mx = fmaxf(mx, __shfl_xor(mx, 1));
                    mx = fmaxf(mx, __shfl_xor(mx, 2));
                    mx = fmaxf(mx, __shfl_xor(mx, 4));
                    mx = fmaxf(mx, __shfl_xor(mx, 8));
                    float e0 = expf(a0 - mx), e1 = expf(a1 - mx);
                    float e2 = expf(a2 - mx), e3 = expf(a3 - mx);
                    float s = e0 + e1 + e2 + e3;
                    s += __shfl_xor(s, 1);
                    s += __shfl_xor(s, 2);
                    s += __shfl_xor(s, 4);
                    s += __shfl_xor(s, 8);
                    float inv = 1.f / s;
                    pr[r][0] = e0 * inv; pr[r][1] = e1 * inv;
                    pr[r][2] = e2 * inv; pr[r][3] = e3 * inv;
                }
                // V^T window fragments once (register-resident across hi/lo passes)
                const short* vr = &sVT[(h * 16 + lq) * VTS];
                int4 v0 = *(const int4*)&vr[quad * 8];
                int4 v1 = *(const int4*)&vr[quad * 8 + 8];
                int4 u0 = *(const int4*)&vr[32 + quad * 8];
                int4 u1 = *(const int4*)&vr[32 + quad * 8 + 8];
                bf16x8 b0 = shiftf(v0, v1, f);
                bf16x8 b1 = shiftf(u0, u1, f);
                // PV with hi+lo bf16 split of P (extra precision margin).
                f32x4 ctx = {0.f, 0.f, 0.f, 0.f};
#pragma unroll
                for (int pass = 0; pass < 2; ++pass) {
#pragma unroll
                    for (int r = 0; r < 4; ++r)
#pragma unroll
                        for (int kt = 0; kt < 4; ++kt) {
                            float p = pr[r][kt];
                            short hi = bfc(p);
                            short v16 = pass == 0 ? hi : bfc(p - b2f(hi));
                            Pb[(quad * 4 + r) * PBS + kt * 16 + lq] = v16;
                        }
                    bf16x8 p0 = *(const bf16x8*)&Pb[lq * PBS + quad * 8];
                    bf16x8 p1 = *(const bf16x8*)&Pb[lq * PBS + 32 + quad * 8];
                    ctx = MFMA16(p0, b0, ctx);
                    ctx = MFMA16(p1, b1, ctx);
                }
                // z = ctx + tq  (tq recomputed from t + stats, fp32)
#pragma unroll
                for (int r = 0; r < 4; ++r) {
                    int row = f * 16 + quad * 4 + r;
                    int col = h * 16 + lq;
                    float tq = (b2f(sT[row * STS + col]) - sMean[row]) * sRstd[row];
                    sT[row * STS + col] = bfc(ctx[r] + tq);
                }
            }
        }
        __syncthreads();

        // ---- x = LN(LN(z)) in place ----
        ln_stats64(sT, tid, 1, sPa, sPb, sMean, sRstd);
        ln_apply64(sT, tid, sMean, sRstd);

        // ---- FFN: z2 = relu(x@W1)@W2 + x -> sT ----
        // H dbuf through sX/sPB (r9); GEMM1 swapped + packed b64 stores (r11).
        {
            const short* w1p = W1T + (size_t)l * 262144;
            const short* w2p = W2T + (size_t)l * 262144;
            bf16x8 XA[4][4];
#pragma unroll
            for (int mt = 0; mt < 4; ++mt)
#pragma unroll
                for (int ks = 0; ks < 4; ++ks)
                    XA[mt][ks] = *(const bf16x8*)&sT[(mt * 16 + lq) * STS + ks * 32 + quad * 8];
            f32x4 yacc[4];
#pragma unroll
            for (int mt = 0; mt < 4; ++mt) yacc[mt] = (f32x4){0.f, 0.f, 0.f, 0.f};
            // prologue: GEMM1 chunk 0 -> sX (buffer 0)
            {
                f32x4 hacc[4];
#pragma unroll
                for (int mt = 0; mt < 4; ++mt) hacc[mt] = (f32x4){0.f, 0.f, 0.f, 0.f};
#pragma unroll
                for (int ks = 0; ks < 4; ++ks) {
                    bf16x8 B1 = *(const bf16x8*)&w1p[(size_t)(w * 16 + lq) * 128 + ks * 32 + quad * 8];
#pragma unroll
                    for (int mt = 0; mt < 4; ++mt) hacc[mt] = MFMA16(B1, XA[mt][ks], hacc[mt]);
                }
#pragma unroll
                for (int mt = 0; mt < 4; ++mt) {
                    s16x4 hv;
#pragma unroll
                    for (int r = 0; r < 4; ++r) hv[r] = bfc(fmaxf(hacc[mt][r], 0.f));
                    *(s16x4*)&sX[(mt * 16 + lq) * STS + w * 16 + quad * 4] = hv;
                }
            }
            __syncthreads();
            for (int c = 0; c < 16; ++c) {
                short* Hr = (c & 1) ? sPB : sX;          // chunk c lives here
                if (c < 15) {
                    short* Hw = (c & 1) ? sX : sPB;      // chunk c+1 target
                    f32x4 hacc[4];
#pragma unroll
                    for (int mt = 0; mt < 4; ++mt) hacc[mt] = (f32x4){0.f, 0.f, 0.f, 0.f};
#pragma unroll
                    for (int ks = 0; ks < 4; ++ks) {
                        bf16x8 B1 = *(const bf16x8*)&w1p[(size_t)((c + 1) * 128 + w * 16 + lq) * 128 + ks * 32 + quad * 8];
#pragma unroll
                        for (int mt = 0; mt < 4; ++mt) hacc[mt] = MFMA16(B1, XA[mt][ks], hacc[mt]);
                    }
#pragma unroll
                    for (int mt = 0; mt < 4; ++mt) {
                        s16x4 hv;
#pragma unroll
                        for (int r = 0; r < 4; ++r) hv[r] = bfc(fmaxf(hacc[mt][r], 0.f));
                        *(s16x4*)&Hw[(mt * 16 + lq) * STS + w * 16 + quad * 4] = hv;
                    }
                }
                // GEMM2(c): wave w -> out cols w*16..+15, accumulate
#pragma unroll
                for (int ks = 0; ks < 4; ++ks) {
                    bf16x8 B2 = *(const bf16x8*)&w2p[(size_t)(w * 16 + lq) * 2048 + c * 128 + ks * 32 + quad * 8];
#pragma unroll
                    for (int mt = 0; mt < 4; ++mt) {
                        bf16x8 A = *(const bf16x8*)&Hr[(mt * 16 + lq) * STS + ks * 32 + quad * 8];
                        yacc[mt] = MFMA16(A, B2, yacc[mt]);
                    }
                }
                __syncthreads();
            }
            // z2 = Y + x
#pragma unroll
            for (int mt = 0; mt < 4; ++mt)
#pragma unroll
                for (int r = 0; r < 4; ++r) {
                    int row = mt * 16 + quad * 4 + r;
                    int col = w * 16 + lq;
                    sT[row * STS + col] = bfc(yacc[mt][r] + b2f(sT[row * STS + col]));
                }
        }
        __syncthreads();

        // ---- t = LN(z2) in place ----
        ln_stats64(sT, tid, 0, sPa, sPb, sMean, sRstd);
        ln_apply64(sT, tid, sMean, sRstd);
    }

    // ================= final single-head attention (d_q = 128) ==============
    // Qf = t @ Wq_f -> sX
    {
        bf16x8 B[4];
#pragma unroll
        for (int ks = 0; ks < 4; ++ks)
            B[ks] = *(const bf16x8*)&WQFT[(w * 16 + lq) * 128 + ks * 32 + quad * 8];
#pragma unroll
        for (int mt = 0; mt < 4; ++mt) {
            f32x4 acc = {0.f, 0.f, 0.f, 0.f};
#pragma unroll
            for (int ks = 0; ks < 4; ++ks) {
                bf16x8 A = *(const bf16x8*)&sT[(mt * 16 + lq) * STS + ks * 32 + quad * 8];
                acc = MFMA16(A, B[ks], acc);
            }
#pragma unroll
            for (int r = 0; r < 4; ++r)
                sX[(mt * 16 + quad * 4 + r) * STS + w * 16 + lq] = bfc(acc[r]);
        }
    }
    // stage kf/vf + score buffer in sPB (dead)
    short* kfL = sPB;
    short* vfL = sPB + 16 * STS;
    float* scF = (float*)(sPB + 2 * 16 * STS);       // [64][17] fp32
    for (int o = tid; o < 2048; o += 512) {
        kfL[(o >> 7) * STS + (o & 127)] = bfc(kf[o]);
        vfL[(o >> 7) * STS + (o & 127)] = bfc(vf[o]);
    }
    __syncthreads();
    // scores[m][k] = Qf[m] . kf[k] / sqrt(128)
    if (tid < 256) {
        int m = tid >> 2, kq = tid & 3;
        float a4[4] = {0.f, 0.f, 0.f, 0.f};
        for (int d8 = 0; d8 < 16; ++d8) {
            bf16x8 qc = *(const bf16x8*)&sX[m * STS + d8 * 8];
            float qf[8];
#pragma unroll
            for (int e = 0; e < 8; ++e) qf[e] = b2f(qc[e]);
#pragma unroll
            for (int k = 0; k < 4; ++k) {
                bf16x8 kc = *(const bf16x8*)&kfL[(kq * 4 + k) * STS + d8 * 8];
#pragma unroll
                for (int e = 0; e < 8; ++e) a4[k] += qf[e] * b2f(kc[e]);
            }
        }
#pragma unroll
        for (int k = 0; k < 4; ++k)
            scF[m * 17 + kq * 4 + k] = a4[k] * 0.08838834764831845f;
    }
    __syncthreads();
    if (tid < 64) {
        float* row = scF + tid * 17;
        float mx = row[0];
#pragma unroll
        for (int k = 1; k < 16; ++k) mx = fmaxf(mx, row[k]);
        float sum = 0.f;
#pragma unroll
        for (int k = 0; k < 16; ++k) { float e = expf(row[k] - mx); row[k] = e; sum += e; }
        float inv = 1.f / sum;
#pragma unroll
        for (int k = 0; k < 16; ++k) row[k] *= inv;
    }
    __syncthreads();
    // z3 = attn @ vf + t -> sX
    {
        int jj = tid & 127, rr0 = tid >> 7;
        float vv[16];
#pragma unroll
        for (int k = 0; k < 16; ++k) vv[k] = b2f(vfL[k * STS + jj]);
#pragma unroll 4
        for (int rr = 0; rr < 16; ++rr) {
            int row = rr0 + 4 * rr;
            float acc = 0.f;
#pragma unroll
            for (int k = 0; k < 16; ++k) acc += scF[row * 17 + k] * vv[k];
            sX[row * STS + jj] = bfc(acc + b2f(sT[row * STS + jj]));
        }
    }
    __syncthreads();
    // out = LN(z3), fp32
    ln_stats64(sX, tid, 0, sPa, sPb, sMean, sRstd);
    for (int o = tid; o < MROWS * 128; o += 512) {
        int r = o >> 7;
        out[(size_t)T0 * 2048 + o] = (b2f(sX[r * STS + (o & 127)]) - sMean[r]) * sRstd[r];
    }
}

extern "C" void kernel_launch(void* const* d_in, const int* in_sizes, int n_in,
                              void* d_out, int out_size, void* d_ws, size_t ws_size,
                              hipStream_t stream) {
    const float* g      = (const float*)d_in[0];
    const float* lf     = (const float*)d_in[1];
    const float* Wvis   = (const float*)d_in[2];
    const float* Wtxt   = (const float*)d_in[3];
    const float* Wq_enc = (const float*)d_in[4];
    const float* Wk_enc = (const float*)d_in[5];
    const float* Wv_enc = (const float*)d_in[6];
    const float* W1f    = (const float*)d_in[7];
    const float* W2f    = (const float*)d_in[8];
    const float* Wqf    = (const float*)d_in[9];
    const float* Wkf    = (const float*)d_in[10];
    const float* Wvf    = (const float*)d_in[11];
    float* out = (float*)d_out;
    float* ws  = (float*)d_ws;

    short* WVH  = (short*)(ws + OFF_WVH);
    short* WVL  = (short*)(ws + OFF_WVL);
    short* WKVH = (short*)(ws + OFF_WKVH);
    short* WKVL = (short*)(ws + OFF_WKVL);
    short* kvB  = (short*)(ws + OFF_KV);
    float* text = ws + OFF_TEXT;
    float* kfp  = ws + OFF_KF;
    float* vfp  = ws + OFF_VF;
    short* W1T  = (short*)(ws + OFF_W1T);
    short* W2T  = (short*)(ws + OFF_W2T);
    short* WQT  = (short*)(ws + OFF_WQT);
    short* WQFT = (short*)(ws + OFF_WQFT);

    // zero only the 63 pad rows at the head of each bf16 K/V array
    for (int a = 0; a < 4; ++a)
        hipMemsetAsync(kvB + (size_t)a * ASTRIDE, 0, (size_t)PAD * DM * sizeof(short), stream);

    k_wcvt <<<dim3(64, 7), dim3(256), 0, stream>>>(Wq_enc, W1f, W2f, Wqf, Wk_enc, Wv_enc, Wvis,
                                                   W1T, W2T, WQT, WQFT, WKVH, WKVL, WVH, WVL);
    k_viskv<<<dim3(TFRAMES / 16), dim3(512), 0, stream>>>(lf, WVH, WVL, WKVH, WKVL, kvB);
    k_text <<<dim3(NG), dim3(128), 0, stream>>>(g, Wtxt, Wkf, Wvf, text, kfp, vfp);
    k_frames<<<dim3(TFRAMES / FPB), dim3(512), 0, stream>>>(kvB, text, kfp, vfp, W1T, W2T, WQT, WQFT, out);
}

// Round 13
// 527.067 us; speedup vs baseline: 1.1450x; 1.0398x over previous
//
#include <hip/hip_runtime.h>
#include <math.h>

#define TFRAMES 4096
#define DM 128
#define LQ 64
#define NG 16
#define NH 8
#define DQH 16
#define FD 2048
#define GFD 512
#define PAD 63
#define KVROWS (TFRAMES + PAD)      /* 4159 */
#define ASTRIDE (KVROWS * DM)       /* 532352 SHORTS per bf16 K/V array */
#define FPB 4                       /* frames per block */
#define MROWS (FPB * NG)            /* 64 state rows per block */
#define STS 136                     /* state row stride (shorts, mult of 8) */
#define VTS 72                      /* V^T row stride (shorts) */
#define PBS 72                      /* P buffer row stride (shorts) */
#define UROWS (LQ + FPB - 1)        /* 67 K/V union rows */

/* ws layout (floats). */
#define OFF_WVH  0                                 /* Wvis^T hi: 128x2048 sh = 131072 fl */
#define OFF_WVL  131072
#define OFF_WKVH 262144                            /* Wk/Wv^T hi: 4x16384 sh = 32768 fl */
#define OFF_WKVL 294912
#define OFF_KV   (TFRAMES * DM)                    /* 524288 */
#define OFF_TEXT (OFF_KV + 2 * ASTRIDE)
#define OFF_KF   (OFF_TEXT + NG * DM)
#define OFF_VF   (OFF_KF + NG * DM)
#define OFF_W1T  (OFF_VF + NG * DM)
#define OFF_W2T  (OFF_W1T + 262144)
#define OFF_WQT  (OFF_W2T + 262144)
#define OFF_WQFT (OFF_WQT + 16384)

typedef __attribute__((ext_vector_type(8))) short bf16x8;
typedef __attribute__((ext_vector_type(4))) short s16x4;
typedef __attribute__((ext_vector_type(4))) float f32x4;
#define MFMA16(a, b, c) __builtin_amdgcn_mfma_f32_16x16x32_bf16(a, b, c, 0, 0, 0)

// f32->bf16 RNE via the compiler's native __bf16 cast (r8-verified: PASS,
// VALUBusy 38->33%, dur 442->432; bit-identical absmax).
__device__ __forceinline__ short bfc(float x) {
    union { __bf16 b; short s; } v;
    v.b = (__bf16)x;
    return v.s;
}
__device__ __forceinline__ float b2f(short s) {
    union { unsigned u; float f; } v;
    v.u = ((unsigned)(unsigned short)s) << 16;
    return v.f;
}
// Extract 8 shorts starting at short-offset f (0..3) from the 12-short window
// {a.x..a.w, b.x, b.y}. v_alignbit_b32 shift is 5-bit (wraps at 32!), so split
// f into a word offset (wo = f>>1, uniform select) + residual 0/16-bit shift.
__device__ __forceinline__ bf16x8 shiftf(int4 a, int4 b, int f) {
    const int wo = f >> 1;
    const int sh = (f & 1) * 16;
    int w0 = wo ? a.y : a.x;
    int w1 = wo ? a.z : a.y;
    int w2 = wo ? a.w : a.z;
    int w3 = wo ? b.x : a.w;
    int w4 = wo ? b.y : b.x;
    int o0 = __builtin_amdgcn_alignbit(w1, w0, sh);
    int o1 = __builtin_amdgcn_alignbit(w2, w1, sh);
    int o2 = __builtin_amdgcn_alignbit(w3, w2, sh);
    int o3 = __builtin_amdgcn_alignbit(w4, w3, sh);
    int4 o = {o0, o1, o2, o3};
    return *(bf16x8*)&o;
}

// -------- kernel W: unified coalesced LDS tile-transpose of all weights ------
__global__ __launch_bounds__(256) void k_wcvt(const float* __restrict__ Wq_enc,
                                              const float* __restrict__ W1f,
                                              const float* __restrict__ W2f,
                                              const float* __restrict__ Wqf,
                                              const float* __restrict__ Wk_enc,
                                              const float* __restrict__ Wv_enc,
                                              const float* __restrict__ Wvis,
                                              short* __restrict__ W1T,
                                              short* __restrict__ W2T,
                                              short* __restrict__ WQT,
                                              short* __restrict__ WQFT,
                                              short* __restrict__ WKVH,
                                              short* __restrict__ WKVL,
                                              short* __restrict__ WVH,
                                              short* __restrict__ WVL) {
    __shared__ float tile[64][65];
    const int tid = threadIdx.x;
    const int gy = blockIdx.y, gx = blockIdx.x;
    const float* src; short* dst; short* dstL = nullptr;
    int sstride, dstride, tr, tc;
    if (gy < 2) {            // W1: [128][2048] -> W1T [2048][128]
        src = W1f + (size_t)gy * 262144; dst = W1T + gy * 262144;
        sstride = 2048; dstride = 128; tr = gx >> 5; tc = gx & 31;
    } else if (gy < 4) {     // W2: [2048][128] -> W2T [128][2048]
        int l = gy - 2;
        src = W2f + (size_t)l * 262144; dst = W2T + l * 262144;
        sstride = 128; dstride = 2048; tr = gx >> 1; tc = gx & 1;
    } else if (gy == 4) {    // WQ l0,l1, WQF: [128][128]
        if (gx >= 12) return;
        int t = gx >> 2;
        src = (t < 2) ? Wq_enc + (size_t)t * 16384 : Wqf;
        dst = (t < 2) ? WQT + t * 16384 : WQFT;
        sstride = 128; dstride = 128; tr = (gx >> 1) & 1; tc = gx & 1;
    } else if (gy == 5) {    // WKV hi/lo: a = 2l + isV
        if (gx >= 16) return;
        int a = gx >> 2;
        src = ((a & 1) ? Wv_enc : Wk_enc) + (size_t)(a >> 1) * 16384;
        dst = WKVH + a * 16384; dstL = WKVL + a * 16384;
        sstride = 128; dstride = 128; tr = (gx >> 1) & 1; tc = gx & 1;
    } else {                 // Wvis: [2048][128] -> WVH/WVL [128][2048]
        src = Wvis; dst = WVH; dstL = WVL;
        sstride = 128; dstride = 2048; tr = gx >> 1; tc = gx & 1;
    }
    const int rb = tr * 64, cb = tc * 64;
    for (int o = tid; o < 64 * 64; o += 256) {
        int r = o >> 6, c = o & 63;
        tile[r][c] = src[(size_t)(rb + r) * sstride + cb + c];
    }
    __syncthreads();
    for (int o = tid; o < 64 * 64; o += 256) {
        int rn = o >> 6, ck = o & 63;
        float v = tile[ck][rn];
        short hi = bfc(v);
        size_t di = (size_t)(cb + rn) * dstride + rb + ck;
        dst[di] = hi;
        if (dstL) dstL[di] = bfc(v - b2f(hi));
    }
}

// -------- kernel P: visual=lf@Wvis, LN, K/V=visn@Wk/Wv — all MFMA, hi/lo -----
// 3-pass hi/lo (AhBh + AlBh + AhBl) keeps ~fp32 accuracy end to end.
// r10: 512 thr. r12: float4 staging + reg prefetch (-23us, latency-bound
// confirmed). r13: LDS double-buffered staging — write chunk c+1 into the
// alternate buffer during chunk-c MFMAs -> 1 barrier/chunk instead of 2.
__global__ __launch_bounds__(512) void k_viskv(const float* __restrict__ lf,
                                               const short* __restrict__ WVH,
                                               const short* __restrict__ WVL,
                                               const short* __restrict__ WKVH,
                                               const short* __restrict__ WKVL,
                                               short* __restrict__ kvB) {
    __shared__ __align__(16) char smem[26112];   // Ah0|Al0|Ah1|Al1 / vis | Vh | Vl
    __shared__ float sPa[256], sPb[256], sMean[16], sRstd[16];
    short* Ah0 = (short*)smem;                 // [16][136] bf16 (4352 B each)
    short* Al0 = (short*)(smem + 4352);
    short* Ah1 = (short*)(smem + 8704);
    short* Al1 = (short*)(smem + 13056);
    float* vis = (float*)smem;                 // [16][132] fp32 (overlays buf0 after ph1)
    short* Vh = (short*)(smem + 17408);        // [16][136]
    short* Vl = (short*)(smem + 21760);        // [16][136]

    const int tid = threadIdx.x;              // 512 = 8 waves
    const int w = tid >> 6;                   // wave 0..7 -> out cols w*16..+15
    const int lane = tid & 63;
    const int lq = lane & 15;
    const int quad = lane >> 4;
    const int r0 = blockIdx.x * 16;           // 256 blocks x 16 rows

    // ---- phase 1: visual = lf @ Wvis  (K=2048 in 16 chunks of 128) ----
    const int sr = tid >> 5;                  // staging row 0..15
    const int sj = tid & 31;                  // float4 group 0..31
    const float* lfp = lf + (size_t)(r0 + sr) * FD + sj * 4;
    float4 pf = *(const float4*)lfp;          // chunk 0
    // stage chunk 0 -> buf0
    {
        float4 v = pf;
        short h0 = bfc(v.x), h1 = bfc(v.y), h2 = bfc(v.z), h3 = bfc(v.w);
        s16x4 hv = {h0, h1, h2, h3};
        s16x4 lv = {bfc(v.x - b2f(h0)), bfc(v.y - b2f(h1)),
                    bfc(v.z - b2f(h2)), bfc(v.w - b2f(h3))};
        *(s16x4*)&Ah0[sr * 136 + sj * 4] = hv;
        *(s16x4*)&Al0[sr * 136 + sj * 4] = lv;
    }
    pf = *(const float4*)(lfp + 128);         // prefetch chunk 1
    __syncthreads();
    f32x4 a0 = {0.f, 0.f, 0.f, 0.f};
    f32x4 a1 = {0.f, 0.f, 0.f, 0.f};
    f32x4 a2 = {0.f, 0.f, 0.f, 0.f};
    for (int c = 0; c < 16; ++c) {
        const short* Ah = (c & 1) ? Ah1 : Ah0;
        const short* Al = (c & 1) ? Al1 : Al0;
#pragma unroll
        for (int ks = 0; ks < 4; ++ks) {
            bf16x8 ah = *(const bf16x8*)&Ah[lq * 136 + ks * 32 + quad * 8];
            bf16x8 al = *(const bf16x8*)&Al[lq * 136 + ks * 32 + quad * 8];
            const size_t bo = (size_t)(w * 16 + lq) * FD + c * 128 + ks * 32 + quad * 8;
            bf16x8 bh = *(const bf16x8*)&WVH[bo];
            bf16x8 bl = *(const bf16x8*)&WVL[bo];
            a0 = MFMA16(ah, bh, a0);
            a1 = MFMA16(al, bh, a1);
            a2 = MFMA16(ah, bl, a2);
        }
        if (c < 15) {
            short* Wh = (c & 1) ? Ah0 : Ah1;  // buffer for chunk c+1
            short* Wl = (c & 1) ? Al0 : Al1;
            float4 v = pf;
            short h0 = bfc(v.x), h1 = bfc(v.y), h2 = bfc(v.z), h3 = bfc(v.w);
            s16x4 hv = {h0, h1, h2, h3};
            s16x4 lv = {bfc(v.x - b2f(h0)), bfc(v.y - b2f(h1)),
                        bfc(v.z - b2f(h2)), bfc(v.w - b2f(h3))};
            *(s16x4*)&Wh[sr * 136 + sj * 4] = hv;
            *(s16x4*)&Wl[sr * 136 + sj * 4] = lv;
            if (c < 14) pf = *(const float4*)(lfp + (c + 2) * 128);
        }
        __syncthreads();
    }
    f32x4 acc = a0 + a1 + a2;
    // C-layout -> vis[row][col] fp32 (row = quad*4+r, col = w*16+lq)
    // (prior barrier covers last chunk's reads before vis overlays buf0)
#pragma unroll
    for (int r = 0; r < 4; ++r)
        vis[(quad * 4 + r) * 132 + w * 16 + lq] = acc[r];
    __syncthreads();

    // ---- phase 2: LN over 128 cols per row (exact 256-thread tree kept;
    //      threads >=256 idle here) ----
    if (tid < 256) {
        int row = tid >> 4, p = tid & 15;     // 8 cols per thread
        float s = 0.f, s2 = 0.f;
#pragma unroll
        for (int k = 0; k < 8; ++k) { float v = vis[row * 132 + p * 8 + k]; s += v; s2 += v * v; }
        sPa[tid] = s; sPb[tid] = s2;
    }
    __syncthreads();
    if (tid < 16) {
        float s = 0.f, s2 = 0.f;
#pragma unroll
        for (int p = 0; p < 16; ++p) { s += sPa[tid * 16 + p]; s2 += sPb[tid * 16 + p]; }
        float m = s * (1.f / 128.f);
        float v = s2 * (1.f / 128.f) - m * m;
        sMean[tid] = m; sRstd[tid] = rsqrtf(v + 1e-5f);
    }
    __syncthreads();
    for (int o = tid; o < 16 * 128; o += 512) {
        int r = o >> 7, j = o & 127;
        float v = (vis[r * 132 + j] - sMean[r]) * sRstd[r];
        short hi = bfc(v);
        Vh[r * 136 + j] = hi;
        Vl[r * 136 + j] = bfc(v - b2f(hi));
    }
    __syncthreads();

    // ---- phase 3: K/V = visn @ Wk/Wv per array (K=128), bf16 out ----
    for (int a = 0; a < 4; ++a) {
        f32x4 k0 = {0.f, 0.f, 0.f, 0.f};
        f32x4 k1 = {0.f, 0.f, 0.f, 0.f};
        f32x4 k2 = {0.f, 0.f, 0.f, 0.f};
#pragma unroll
        for (int ks = 0; ks < 4; ++ks) {
            bf16x8 ah = *(const bf16x8*)&Vh[lq * 136 + ks * 32 + quad * 8];
            bf16x8 al = *(const bf16x8*)&Vl[lq * 136 + ks * 32 + quad * 8];
            const size_t bo = (size_t)a * 16384 + (size_t)(w * 16 + lq) * 128 + ks * 32 + quad * 8;
            bf16x8 bh = *(const bf16x8*)&WKVH[bo];
            bf16x8 bl = *(const bf16x8*)&WKVL[bo];
            k0 = MFMA16(ah, bh, k0);
            k1 = MFMA16(al, bh, k1);
            k2 = MFMA16(ah, bl, k2);
        }
        f32x4 ka = k0 + k1 + k2;
#pragma unroll
        for (int r = 0; r < 4; ++r)
            kvB[(size_t)a * ASTRIDE + (size_t)(PAD + r0 + quad * 4 + r) * DM + w * 16 + lq]
                = bfc(ka[r]);
    }
}

// -------- kernel 3: text = g @ W_txt ; Kf = text @ Wk_f ; Vf = text @ Wv_f ---
__global__ __launch_bounds__(128) void k_text(const float* __restrict__ g,
                                              const float* __restrict__ Wtxt,
                                              const float* __restrict__ Wkf,
                                              const float* __restrict__ Wvf,
                                              float* __restrict__ text,
                                              float* __restrict__ kf,
                                              float* __restrict__ vf) {
    __shared__ float gs[GFD];
    __shared__ float tr[DM];
    const int r = blockIdx.x;
    const int tid = threadIdx.x;
    for (int i = tid; i < GFD; i += 128) gs[i] = g[(size_t)r * GFD + i];
    __syncthreads();
    float acc = 0.f;
    for (int k = 0; k < GFD; ++k) acc += gs[k] * Wtxt[(size_t)k * DM + tid];
    tr[tid] = acc;
    text[(size_t)r * DM + tid] = acc;
    __syncthreads();
    float a1 = 0.f, a2 = 0.f;
    for (int k = 0; k < DM; ++k) {
        float x = tr[k];
        a1 += x * Wkf[(size_t)k * DM + tid];
        a2 += x * Wvf[(size_t)k * DM + tid];
    }
    kf[(size_t)r * DM + tid] = a1;
    vf[(size_t)r * DM + tid] = a2;
}

// ---------------- LN helpers for [64][STS] bf16 LDS tile ---------------------
__device__ __forceinline__ void ln_stats64(const short* buf, int tid, int dbl,
                                           float* pa, float* pb, float* ms, float* rs) {
    {
        int row = tid >> 3, p = tid & 7;
        const bf16x8* bp = (const bf16x8*)(buf + row * STS + p * 16);
        float s = 0.f, s2 = 0.f;
#pragma unroll
        for (int q8 = 0; q8 < 2; ++q8) {
            bf16x8 x = bp[q8];
#pragma unroll
            for (int e = 0; e < 8; ++e) { float v = b2f(x[e]); s += v; s2 += v * v; }
        }
        pa[tid] = s; pb[tid] = s2;
    }
    __syncthreads();
    if (tid < 64) {
        float ss = 0.f, ss2 = 0.f;
#pragma unroll
        for (int p2 = 0; p2 < 8; ++p2) { ss += pa[tid * 8 + p2]; ss2 += pb[tid * 8 + p2]; }
        float m = ss * (1.f / 128.f);
        float v = ss2 * (1.f / 128.f) - m * m;
        float r = rsqrtf(v + 1e-5f);
        if (dbl) r *= rsqrtf(v / (v + 1e-5f) + 1e-5f);   // exact LN(LN(x)) fold
        ms[tid] = m; rs[tid] = r;
    }
    __syncthreads();
}
__device__ __forceinline__ void ln_apply64(short* buf, int tid,
                                           const float* ms, const float* rs) {
    int row = tid >> 3, p = tid & 7;
    float m = ms[row], r = rs[row];
    bf16x8* bp = (bf16x8*)(buf + row * STS + p * 16);
#pragma unroll
    for (int q8 = 0; q8 < 2; ++q8) {
        bf16x8 x = bp[q8]; bf16x8 o;
#pragma unroll
        for (int e = 0; e < 8; ++e) o[e] = bfc((b2f(x[e]) - m) * r);
        bp[q8] = o;
    }
    __syncthreads();
}

// ---------------- kernel 4: 4 frames/block, MFMA attention + FFN -------------
__global__ __launch_bounds__(512, 4) void k_frames(
    const short* __restrict__ kvB,    const float* __restrict__ text,
    const float* __restrict__ kf,     const float* __restrict__ vf,
    const short* __restrict__ W1T,    const short* __restrict__ W2T,
    const short* __restrict__ WQT,    const short* __restrict__ WQFT,
    float* __restrict__ out) {
    __shared__ __align__(16) short sT[MROWS * STS];     // state (t / z / x / z2)
    __shared__ __align__(16) short sX[MROWS * STS];     // Q / H-chunk / Qf / z3
    __shared__ __align__(16) short sVT[128 * VTS];      // V^T union (dims x keys)
    __shared__ __align__(16) short sPB[8 * 16 * PBS];   // LN(t) copy; per-wave P; FFN H dbuf; kf/vf/scores
    __shared__ float sPa[512], sPb[512];
    __shared__ float sMean[64], sRstd[64];

    const int tid = threadIdx.x;        // 512 = 8 waves
    const int w = tid >> 6;             // wave 0..7
    const int lane = tid & 63;
    const int lq = lane & 15;
    const int quad = lane >> 4;
    // XCD-aware swizzle (T1): keeps each XCD on a contiguous frame chunk
    // (FETCH 115->99 MB verified r0->r6; time-neutral but strictly less HBM).
    const int bswz = (blockIdx.x & 7) * 128 + (blockIdx.x >> 3);
    const int T0 = bswz * FPB;

    // init: t rows m = f*16+q <- text[q][:]
    for (int o = tid; o < MROWS * 128; o += 512)
        sT[(o >> 7) * STS + (o & 127)] = bfc(text[((o >> 7) & 15) * 128 + (o & 127)]);
    __syncthreads();

    for (int l = 0; l < 2; ++l) {
        const short* kvK = kvB + (size_t)(2 * l) * ASTRIDE;
        const short* kvV = kvB + (size_t)(2 * l + 1) * ASTRIDE;

        // ---- stage V^T union (coalesced; barrier inside ln_stats covers it) --
        for (int o = tid; o < UROWS * 128; o += 512) {
            int u = o >> 7, d = o & 127;
            sVT[d * VTS + u] = kvV[(size_t)(T0 + u) * 128 + d];
        }
        ln_stats64(sT, tid, 0, sPa, sPb, sMean, sRstd);

        // ---- normalize t ONCE -> sPB (r12; bit-identical Q) ----
        {
            int row = tid >> 3, p = tid & 7;
            float m = sMean[row], r = sRstd[row];
            const bf16x8* tp = (const bf16x8*)(sT + row * STS + p * 16);
            bf16x8* np = (bf16x8*)(sPB + row * STS + p * 16);
#pragma unroll
            for (int q8 = 0; q8 < 2; ++q8) {
                bf16x8 x = tp[q8]; bf16x8 o;
#pragma unroll
                for (int e = 0; e < 8; ++e) o[e] = bfc((b2f(x[e]) - m) * r);
                np[q8] = o;
            }
        }
        __syncthreads();

        // ---- Q = LN(t) @ Wq[l] -> sX (plain MFMA reads of the shared copy) --
        {
            const short* wq = WQT + (size_t)l * 16384;
            bf16x8 B[4];
#pragma unroll
            for (int ks = 0; ks < 4; ++ks)
                B[ks] = *(const bf16x8*)&wq[(w * 16 + lq) * 128 + ks * 32 + quad * 8];
#pragma unroll
            for (int mt = 0; mt < 4; ++mt) {
                f32x4 acc = {0.f, 0.f, 0.f, 0.f};
#pragma unroll
                for (int ks = 0; ks < 4; ++ks) {
                    bf16x8 a8 = *(const bf16x8*)&sPB[(mt * 16 + lq) * STS + ks * 32 + quad * 8];
                    acc = MFMA16(a8, B[ks], acc);
                }
#pragma unroll
                for (int r4 = 0; r4 < 4; ++r4)
                    sX[(mt * 16 + quad * 4 + r4) * STS + w * 16 + lq] = bfc(acc[r4]);
            }
        }
        __syncthreads();

        // ---- attention: wave pair (2f, 2f+1) handles frame f, 4 heads each --
        {
            const int f = w >> 1;
            const int hg = (w & 1) * 4;
            short* Pb = sPB + w * 16 * PBS;
            bf16x8 zv = {};
            for (int hh = 0; hh < 4; ++hh) {
                const int h = hg + hh;
                bf16x8 aq;
                {
                    bf16x8 t8 = *(const bf16x8*)&sX[(f * 16 + lq) * STS + h * 16 + (quad & 1) * 8];
                    aq = (quad < 2) ? t8 : zv;
                }
                f32x4 sc4[4];
#pragma unroll
                for (int kt = 0; kt < 4; ++kt) {
                    bf16x8 bk = *(const bf16x8*)&kvK[(size_t)(T0 + f + kt * 16 + lq) * 128 + h * 16 + (quad & 1) * 8];
                    bk = (quad < 2) ? bk : zv;
                    f32x4 z4 = {0.f, 0.f, 0.f, 0.f};
                    sc4[kt] = MFMA16(aq, bk, z4);
                }
                // softmax in C-layout registers; __expf (r13: v_exp fast path,
                // rel err ~1e-6 << bf16 rounding)
                float pr[4][4];   // [r][kt]
#pragma unroll
                for (int r = 0; r < 4; ++r) {
                    float a0 = sc4[0][r] * 0.25f, a1 = sc4[1][r] * 0.25f;
                    float a2 = sc4[2][r] * 0.25f, a3 = sc4[3][r] * 0.25f;
                    float mx = fmaxf(fmaxf(a0, a1), fmaxf(a2, a3));
                    mx = fmaxf(mx, __shfl_xor(mx, 1));
                    mx = fmaxf(mx, __shfl_xor(mx, 2));
                    mx = fmaxf(mx, __shfl_xor(mx, 4));
                    mx = fmaxf(mx, __shfl_xor(mx, 8));
                    float e0 = __expf(a0 - mx), e1 = __expf(a1 - mx);
                    float e2 = __expf(a2 - mx), e3 = __expf(a3 - mx);
                    float s = e0 + e1 + e2 + e3;
                    s += __shfl_xor(s, 1);
                    s += __shfl_xor(s, 2);
                    s += __shfl_xor(s, 4);
                    s += __shfl_xor(s, 8);
                    float inv = 1.f / s;
                    pr[r][0] = e0 * inv; pr[r][1] = e1 * inv;
                    pr[r][2] = e2 * inv; pr[r][3] = e3 * inv;
                }
                // V^T window fragments once (register-resident across hi/lo passes)
                const short* vr = &sVT[(h * 16 + lq) * VTS];
                int4 v0 = *(const int4*)&vr[quad * 8];
                int4 v1 = *(const int4*)&vr[quad * 8 + 8];
                int4 u0 = *(const int4*)&vr[32 + quad * 8];
                int4 u1 = *(const int4*)&vr[32 + quad * 8 + 8];
                bf16x8 b0 = shiftf(v0, v1, f);
                bf16x8 b1 = shiftf(u0, u1, f);
                // PV with hi+lo bf16 split of P (extra precision margin).
                f32x4 ctx = {0.f, 0.f, 0.f, 0.f};
#pragma unroll
                for (int pass = 0; pass < 2; ++pass) {
#pragma unroll
                    for (int r = 0; r < 4; ++r)
#pragma unroll
                        for (int kt = 0; kt < 4; ++kt) {
                            float p = pr[r][kt];
                            short hi = bfc(p);
                            short v16 = pass == 0 ? hi : bfc(p - b2f(hi));
                            Pb[(quad * 4 + r) * PBS + kt * 16 + lq] = v16;
                        }
                    bf16x8 p0 = *(const bf16x8*)&Pb[lq * PBS + quad * 8];
                    bf16x8 p1 = *(const bf16x8*)&Pb[lq * PBS + 32 + quad * 8];
                    ctx = MFMA16(p0, b0, ctx);
                    ctx = MFMA16(p1, b1, ctx);
                }
                // z = ctx + tq  (tq recomputed from t + stats, fp32)
#pragma unroll
                for (int r = 0; r < 4; ++r) {
                    int row = f * 16 + quad * 4 + r;
                    int col = h * 16 + lq;
                    float tq = (b2f(sT[row * STS + col]) - sMean[row]) * sRstd[row];
                    sT[row * STS + col] = bfc(ctx[r] + tq);
                }
            }
        }
        __syncthreads();

        // ---- x = LN(LN(z)) in place ----
        ln_stats64(sT, tid, 1, sPa, sPb, sMean, sRstd);
        ln_apply64(sT, tid, sMean, sRstd);

        // ---- FFN: z2 = relu(x@W1)@W2 + x -> sT ----
        // H dbuf through sX/sPB (r9); GEMM1 swapped + packed b64 stores (r11).
        {
            const short* w1p = W1T + (size_t)l * 262144;
            const short* w2p = W2T + (size_t)l * 262144;
            bf16x8 XA[4][4];
#pragma unroll
            for (int mt = 0; mt < 4; ++mt)
#pragma unroll
                for (int ks = 0; ks < 4; ++ks)
                    XA[mt][ks] = *(const bf16x8*)&sT[(mt * 16 + lq) * STS + ks * 32 + quad * 8];
            f32x4 yacc[4];
#pragma unroll
            for (int mt = 0; mt < 4; ++mt) yacc[mt] = (f32x4){0.f, 0.f, 0.f, 0.f};
            // prologue: GEMM1 chunk 0 -> sX (buffer 0)
            {
                f32x4 hacc[4];
#pragma unroll
                for (int mt = 0; mt < 4; ++mt) hacc[mt] = (f32x4){0.f, 0.f, 0.f, 0.f};
#pragma unroll
                for (int ks = 0; ks < 4; ++ks) {
                    bf16x8 B1 = *(const bf16x8*)&w1p[(size_t)(w * 16 + lq) * 128 + ks * 32 + quad * 8];
#pragma unroll
                    for (int mt = 0; mt < 4; ++mt) hacc[mt] = MFMA16(B1, XA[mt][ks], hacc[mt]);
                }
#pragma unroll
                for (int mt = 0; mt < 4; ++mt) {
                    s16x4 hv;
#pragma unroll
                    for (int r = 0; r < 4; ++r) hv[r] = bfc(fmaxf(hacc[mt][r], 0.f));
                    *(s16x4*)&sX[(mt * 16 + lq) * STS + w * 16 + quad * 4] = hv;
                }
            }
            __syncthreads();
            for (int c = 0; c < 16; ++c) {
                short* Hr = (c & 1) ? sPB : sX;          // chunk c lives here
                if (c < 15) {
                    short* Hw = (c & 1) ? sX : sPB;      // chunk c+1 target
                    f32x4 hacc[4];
#pragma unroll
                    for (int mt = 0; mt < 4; ++mt) hacc[mt] = (f32x4){0.f, 0.f, 0.f, 0.f};
#pragma unroll
                    for (int ks = 0; ks < 4; ++ks) {
                        bf16x8 B1 = *(const bf16x8*)&w1p[(size_t)((c + 1) * 128 + w * 16 + lq) * 128 + ks * 32 + quad * 8];
#pragma unroll
                        for (int mt = 0; mt < 4; ++mt) hacc[mt] = MFMA16(B1, XA[mt][ks], hacc[mt]);
                    }
#pragma unroll
                    for (int mt = 0; mt < 4; ++mt) {
                        s16x4 hv;
#pragma unroll
                        for (int r = 0; r < 4; ++r) hv[r] = bfc(fmaxf(hacc[mt][r], 0.f));
                        *(s16x4*)&Hw[(mt * 16 + lq) * STS + w * 16 + quad * 4] = hv;
                    }
                }
                // GEMM2(c): wave w -> out cols w*16..+15, accumulate
#pragma unroll
                for (int ks = 0; ks < 4; ++ks) {
                    bf16x8 B2 = *(const bf16x8*)&w2p[(size_t)(w * 16 + lq) * 2048 + c * 128 + ks * 32 + quad * 8];
#pragma unroll
                    for (int mt = 0; mt < 4; ++mt) {
                        bf16x8 A = *(const bf16x8*)&Hr[(mt * 16 + lq) * STS + ks * 32 + quad * 8];
                        yacc[mt] = MFMA16(A, B2, yacc[mt]);
                    }
                }
                __syncthreads();
            }
            // z2 = Y + x
#pragma unroll
            for (int mt = 0; mt < 4; ++mt)
#pragma unroll
                for (int r = 0; r < 4; ++r) {
                    int row = mt * 16 + quad * 4 + r;
                    int col = w * 16 + lq;
                    sT[row * STS + col] = bfc(yacc[mt][r] + b2f(sT[row * STS + col]));
                }
        }
        __syncthreads();

        // ---- t = LN(z2) in place ----
        ln_stats64(sT, tid, 0, sPa, sPb, sMean, sRstd);
        ln_apply64(sT, tid, sMean, sRstd);
    }

    // ================= final single-head attention (d_q = 128) ==============
    // Qf = t @ Wq_f -> sX
    {
        bf16x8 B[4];
#pragma unroll
        for (int ks = 0; ks < 4; ++ks)
            B[ks] = *(const bf16x8*)&WQFT[(w * 16 + lq) * 128 + ks * 32 + quad * 8];
#pragma unroll
        for (int mt = 0; mt < 4; ++mt) {
            f32x4 acc = {0.f, 0.f, 0.f, 0.f};
#pragma unroll
            for (int ks = 0; ks < 4; ++ks) {
                bf16x8 A = *(const bf16x8*)&sT[(mt * 16 + lq) * STS + ks * 32 + quad * 8];
                acc = MFMA16(A, B[ks], acc);
            }
#pragma unroll
            for (int r = 0; r < 4; ++r)
                sX[(mt * 16 + quad * 4 + r) * STS + w * 16 + lq] = bfc(acc[r]);
        }
    }
    // stage kf/vf + score buffer in sPB (dead)
    short* kfL = sPB;
    short* vfL = sPB + 16 * STS;
    float* scF = (float*)(sPB + 2 * 16 * STS);       // [64][17] fp32
    for (int o = tid; o < 2048; o += 512) {
        kfL[(o >> 7) * STS + (o & 127)] = bfc(kf[o]);
        vfL[(o >> 7) * STS + (o & 127)] = bfc(vf[o]);
    }
    __syncthreads();
    // scores[m][k] = Qf[m] . kf[k] / sqrt(128)
    if (tid < 256) {
        int m = tid >> 2, kq = tid & 3;
        float a4[4] = {0.f, 0.f, 0.f, 0.f};
        for (int d8 = 0; d8 < 16; ++d8) {
            bf16x8 qc = *(const bf16x8*)&sX[m * STS + d8 * 8];
            float qf[8];
#pragma unroll
            for (int e = 0; e < 8; ++e) qf[e] = b2f(qc[e]);
#pragma unroll
            for (int k = 0; k < 4; ++k) {
                bf16x8 kc = *(const bf16x8*)&kfL[(kq * 4 + k) * STS + d8 * 8];
#pragma unroll
                for (int e = 0; e < 8; ++e) a4[k] += qf[e] * b2f(kc[e]);
            }
        }
#pragma unroll
        for (int k = 0; k < 4; ++k)
            scF[m * 17 + kq * 4 + k] = a4[k] * 0.08838834764831845f;
    }
    __syncthreads();
    if (tid < 64) {
        float* row = scF + tid * 17;
        float mx = row[0];
#pragma unroll
        for (int k = 1; k < 16; ++k) mx = fmaxf(mx, row[k]);
        float sum = 0.f;
#pragma unroll
        for (int k = 0; k < 16; ++k) { float e = __expf(row[k] - mx); row[k] = e; sum += e; }
        float inv = 1.f / sum;
#pragma unroll
        for (int k = 0; k < 16; ++k) row[k] *= inv;
    }
    __syncthreads();
    // z3 = attn @ vf + t -> sX
    {
        int jj = tid & 127, rr0 = tid >> 7;
        float vv[16];
#pragma unroll
        for (int k = 0; k < 16; ++k) vv[k] = b2f(vfL[k * STS + jj]);
#pragma unroll 4
        for (int rr = 0; rr < 16; ++rr) {
            int row = rr0 + 4 * rr;
            float acc = 0.f;
#pragma unroll
            for (int k = 0; k < 16; ++k) acc += scF[row * 17 + k] * vv[k];
            sX[row * STS + jj] = bfc(acc + b2f(sT[row * STS + jj]));
        }
    }
    __syncthreads();
    // out = LN(z3), fp32
    ln_stats64(sX, tid, 0, sPa, sPb, sMean, sRstd);
    for (int o = tid; o < MROWS * 128; o += 512) {
        int r = o >> 7;
        out[(size_t)T0 * 2048 + o] = (b2f(sX[r * STS + (o & 127)]) - sMean[r]) * sRstd[r];
    }
}

extern "C" void kernel_launch(void* const* d_in, const int* in_sizes, int n_in,
                              void* d_out, int out_size, void* d_ws, size_t ws_size,
                              hipStream_t stream) {
    const float* g      = (const float*)d_in[0];
    const float* lf     = (const float*)d_in[1];
    const float* Wvis   = (const float*)d_in[2];
    const float* Wtxt   = (const float*)d_in[3];
    const float* Wq_enc = (const float*)d_in[4];
    const float* Wk_enc = (const float*)d_in[5];
    const float* Wv_enc = (const float*)d_in[6];
    const float* W1f    = (const float*)d_in[7];
    const float* W2f    = (const float*)d_in[8];
    const float* Wqf    = (const float*)d_in[9];
    const float* Wkf    = (const float*)d_in[10];
    const float* Wvf    = (const float*)d_in[11];
    float* out = (float*)d_out;
    float* ws  = (float*)d_ws;

    short* WVH  = (short*)(ws + OFF_WVH);
    short* WVL  = (short*)(ws + OFF_WVL);
    short* WKVH = (short*)(ws + OFF_WKVH);
    short* WKVL = (short*)(ws + OFF_WKVL);
    short* kvB  = (short*)(ws + OFF_KV);
    float* text = ws + OFF_TEXT;
    float* kfp  = ws + OFF_KF;
    float* vfp  = ws + OFF_VF;
    short* W1T  = (short*)(ws + OFF_W1T);
    short* W2T  = (short*)(ws + OFF_W2T);
    short* WQT  = (short*)(ws + OFF_WQT);
    short* WQFT = (short*)(ws + OFF_WQFT);

    // zero only the 63 pad rows at the head of each bf16 K/V array
    for (int a = 0; a < 4; ++a)
        hipMemsetAsync(kvB + (size_t)a * ASTRIDE, 0, (size_t)PAD * DM * sizeof(short), stream);

    k_wcvt <<<dim3(64, 7), dim3(256), 0, stream>>>(Wq_enc, W1f, W2f, Wqf, Wk_enc, Wv_enc, Wvis,
                                                   W1T, W2T, WQT, WQFT, WKVH, WKVL, WVH, WVL);
    k_viskv<<<dim3(TFRAMES / 16), dim3(512), 0, stream>>>(lf, WVH, WVL, WKVH, WKVL, kvB);
    k_text <<<dim3(NG), dim3(128), 0, stream>>>(g, Wtxt, Wkf, Wvf, text, kfp, vfp);
    k_frames<<<dim3(TFRAMES / FPB), dim3(512), 0, stream>>>(kvB, text, kfp, vfp, W1T, W2T, WQT, WQFT, out);
}